// Round 3
// baseline (35319.998 us; speedup 1.0000x reference)
//
#include <hip/hip_runtime.h>
#include <stdint.h>
#include <math.h>

// ---------------------------------------------------------------------------
// Round 20: RESUBMIT of R19 (container failed twice = infra flake; kernel
// audit found no OOB / barrier-divergence / hazard issue). Structure:
// PHASE-OVERLAPPED dual-chain mc_kernel. R18 (7988 us) showed MfmaUtil 40 /
// Occupancy 23 (2 waves/SIMD) -- stall is intra-wave serialization:
// [matmul][barrier][pure-VALU epi][barrier][tail] leaves the matrix pipe
// idle through the whole epilogue. Chains are independent, so interleave
// chain A's epilogue INTO chain B's matmul kb-loop and vice versa
// (2 phases/step, same 2 barriers):
//   phase1: { mm-B(t) kb-slice + 2 regs epi-A(t) } x8 ; wave1: tail-B(t-1)
//   phase2: { mm-A(t+1) kb-slice + 2 regs epi-B(t) } x8 ; wave0: tail-A(t)
// MFMA issues ~1 cyc but occupies pipe 32 -> one wave slides epi VALU under
// its own MFMAs; B-frag L2 latency also hides under epi. Fused loops fully
// unrolled (runtime-indexed ext_vector would go to scratch). Prologue does
// mm-A(0) + one extra barrier; tail-B(19) after the loop.
// ---------------------------------------------------------------------------

#define HH     128
#define NG     512
#define NB     8192
#define NSAMP  100
#define NSTEP  20
#define TCAP   18
#define NHIST  126
#define NRET   127

using bfrag = __attribute__((ext_vector_type(8))) short;   // 8 bf16 = 4 VGPRs
using facc  = __attribute__((ext_vector_type(16))) float;  // 16 f32 acc

// LDS frag strides (shorts): per-(kb,hs) region 264 (8 pad), per-kb 528.
#define SHS 264
#define SKB 528
#define HFN 4224   // 8 kb * 528

// ----------------------------- threefry2x32 --------------------------------
__device__ __forceinline__ void tf2x32(uint32_t k0, uint32_t k1,
                                       uint32_t x0, uint32_t x1,
                                       uint32_t &y0, uint32_t &y1) {
  uint32_t ks2 = k0 ^ k1 ^ 0x1BD11BDAu;
  x0 += k0; x1 += k1;
#define RR(r) { x0 += x1; x1 = (x1 << (r)) | (x1 >> (32 - (r))); x1 ^= x0; }
  RR(13) RR(15) RR(26) RR(6)   x0 += k1;  x1 += ks2 + 1u;
  RR(17) RR(29) RR(16) RR(24)  x0 += ks2; x1 += k0  + 2u;
  RR(13) RR(15) RR(26) RR(6)   x0 += k0;  x1 += k1  + 3u;
  RR(17) RR(29) RR(16) RR(24)  x0 += k1;  x1 += ks2 + 4u;
  RR(13) RR(15) RR(26) RR(6)   x0 += ks2; x1 += k0  + 5u;
#undef RR
  y0 = x0; y1 = x1;
}

__device__ __forceinline__ float erfinv32(float x) {
  float w = -__logf(fmaxf(1.0f - x * x, 1e-37f));
  float p;
  if (w < 5.0f) {
    w = w - 2.5f;
    p = 2.81022636e-08f;
    p = fmaf(p, w, 3.43273939e-07f);
    p = fmaf(p, w, -3.5233877e-06f);
    p = fmaf(p, w, -4.39150654e-06f);
    p = fmaf(p, w, 0.00021858087f);
    p = fmaf(p, w, -0.00125372503f);
    p = fmaf(p, w, -0.00417768164f);
    p = fmaf(p, w, 0.246640727f);
    p = fmaf(p, w, 1.50140941f);
  } else {
    w = sqrtf(w) - 3.0f;
    p = -0.000200214257f;
    p = fmaf(p, w, 0.000100950558f);
    p = fmaf(p, w, 0.00134934322f);
    p = fmaf(p, w, -0.00367342844f);
    p = fmaf(p, w, 0.00573950773f);
    p = fmaf(p, w, -0.0076224613f);
    p = fmaf(p, w, 0.00943887047f);
    p = fmaf(p, w, 1.00167406f);
    p = fmaf(p, w, 2.83297682f);
  }
  return p * x;
}

__device__ __forceinline__ float normal32(uint32_t k0, uint32_t k1, uint32_t idx) {
  uint32_t y0, y1;
  tf2x32(k0, k1, 0u, idx, y0, y1);
  uint32_t bits = y0 ^ y1;
  float f = __uint_as_float((bits >> 9) | 0x3f800000u) - 1.0f;
  const float lo = __uint_as_float(0xBF7FFFFFu);
  float u = fmaxf(lo, f * 2.0f + lo);
  return 1.41421356f * erfinv32(u);
}

__device__ __forceinline__ float fast_sigmoid(float x) {
  return __builtin_amdgcn_rcpf(1.0f + __expf(-x));
}
__device__ __forceinline__ float fast_tanh(float x) {
  return 1.0f - 2.0f * __builtin_amdgcn_rcpf(1.0f + __expf(2.0f * x));
}

// RNE bf16 (one-time B pack only)
__device__ __forceinline__ unsigned short f2bf(float x) {
  uint32_t u = __float_as_uint(x);
  uint32_t r = u + 0x7fffu + ((u >> 16) & 1u);
  return (unsigned short)(r >> 16);
}
__device__ __forceinline__ float bf2f(unsigned short h) {
  return __uint_as_float(((uint32_t)h) << 16);
}

// truncation split: hi = top16(h); lo = top16(h - hi) (Sterbenz-exact sub)
__device__ __forceinline__ void split_trunc(float h, unsigned short &hi,
                                            unsigned short &lo) {
  uint32_t u = __float_as_uint(h);
  hi = (unsigned short)(u >> 16);
  float hv = __uint_as_float(u & 0xFFFF0000u);
  lo = (unsigned short)(__float_as_uint(h - hv) >> 16);
}

// ------------------------------- small kernels -----------------------------
__global__ void returns_kernel(const float* __restrict__ inp,
                               const float* __restrict__ pert,
                               float* __restrict__ ret) {
  int i = blockIdx.x * blockDim.x + threadIdx.x;
  if (i >= NRET * NB) return;
  int s = i / NB, b = i - s * NB;
  float p0 = inp[s * NB + b] * (1.0f + pert[s * NB + b]);
  float p1 = inp[(s + 1) * NB + b] * (1.0f + pert[(s + 1) * NB + b]);
  ret[i] = p1 - p0;
}

__global__ void keys_kernel(uint32_t* __restrict__ keys) {
  int id = blockIdx.x * blockDim.x + threadIdx.x;
  if (id >= NSAMP * NSTEP) return;
  int s = id / NSTEP, t = id - s * NSTEP;
  uint32_t sk0, sk1, k0, k1;
  tf2x32(0u, 42u, 0u, (uint32_t)s, sk0, sk1);
  tf2x32(sk0, sk1, 0u, (uint32_t)t, k0, k1);
  keys[2 * id] = k0; keys[2 * id + 1] = k1;
}

// B-fragment pack (RNE): Bhi/Blo[((gct*8+kb)*64+lane)*8+j]
__global__ void pack_kernel(const float* __restrict__ W_hh,
                            const float* __restrict__ w_mu,
                            const float* __restrict__ w_ls,
                            unsigned short* __restrict__ Bhi,
                            unsigned short* __restrict__ Blo,
                            unsigned short* __restrict__ Bmu) {
  int idx = blockIdx.x * blockDim.x + threadIdx.x;
  if (idx < 65536) {
    int j = idx & 7, lane = (idx >> 3) & 63, kb = (idx >> 9) & 7, gct = idx >> 12;
    int k = kb * 16 + ((lane >> 5) << 3) + j;
    int g = (gct << 5) + (lane & 31);
    float w = W_hh[k * NG + g];
    unsigned short hi = f2bf(w);
    unsigned short lo = f2bf(w - bf2f(hi));
    Bhi[idx] = hi; Blo[idx] = lo;
  } else if (idx < 65536 + 4096) {
    int i2 = idx - 65536;
    int j = i2 & 7, lane = (i2 >> 3) & 63, kb = (i2 >> 9) & 7;
    int k = kb * 16 + ((lane >> 5) << 3) + j;
    int col = lane & 31;
    float v = (col == 0) ? w_mu[k] : (col == 1 ? w_ls[k] : 0.0f);
    Bmu[i2] = f2bf(v);
  }
}

// ------------------------------ history kernel -----------------------------
__launch_bounds__(256, 1)
__global__ void hist_kernel(const float* __restrict__ ret,
                            const float* __restrict__ W_ih,
                            const float* __restrict__ bias,
                            const unsigned short* __restrict__ Bhi,
                            const unsigned short* __restrict__ Blo,
                            float* __restrict__ hout,
                            float* __restrict__ cout) {
  __shared__ unsigned short hfh[2][HFN];
  __shared__ unsigned short hfl[2][HFN];

  const int tid  = threadIdx.x;
  const int lane = tid & 63;
  const int cg   = tid >> 6;
  const int hs   = lane >> 5;
  const int m    = lane & 31;
  const int col  = (cg << 5) + m;
  const int b0   = blockIdx.x << 5;

  float wih_r[4], bb_r[4];
#pragma unroll
  for (int gi = 0; gi < 4; ++gi) {
    wih_r[gi] = W_ih[(gi << 7) + col];
    bb_r[gi]  = bias[(gi << 7) + col];
  }

  const int coff = (col >> 4) * SKB + ((col >> 3) & 1) * SHS + (col & 7);
  const int aoff = hs * SHS + m * 8;

  float c_reg[16];
#pragma unroll
  for (int reg = 0; reg < 16; ++reg) {
    int row32 = (reg & 3) + ((reg >> 2) << 3) + (hs << 2);
    c_reg[reg] = 0.0f;
    hfh[0][coff + row32 * 8] = 0;
    hfl[0][coff + row32 * 8] = 0;
  }
  __syncthreads();

  int buf = 0;
#pragma unroll 1
  for (int t = 0; t < NHIST; ++t) {
    const int nbuf = buf ^ 1;
    facc acc[4];
#pragma unroll
    for (int reg = 0; reg < 16; ++reg) {
      int row32 = (reg & 3) + ((reg >> 2) << 3) + (hs << 2);
      float xv = ret[t * NB + b0 + row32];
#pragma unroll
      for (int gi = 0; gi < 4; ++gi)
        acc[gi][reg] = fmaf(xv, wih_r[gi], bb_r[gi]);
    }
#pragma unroll 1
    for (int kb = 0; kb < 8; ++kb) {
      bfrag ah = *(const bfrag*)&hfh[buf][kb * SKB + aoff];
      bfrag al = *(const bfrag*)&hfl[buf][kb * SKB + aoff];
#pragma unroll
      for (int gp = 0; gp < 2; ++gp) {
        const int g0 = 2 * gp, g1 = 2 * gp + 1;
        const int off0 = ((((g0 << 2) + cg) << 3) + kb) * 512 + lane * 8;
        const int off1 = ((((g1 << 2) + cg) << 3) + kb) * 512 + lane * 8;
        bfrag bh0 = *(const bfrag*)&Bhi[off0];
        bfrag bl0 = *(const bfrag*)&Blo[off0];
        bfrag bh1 = *(const bfrag*)&Bhi[off1];
        bfrag bl1 = *(const bfrag*)&Blo[off1];
        acc[g0] = __builtin_amdgcn_mfma_f32_32x32x16_bf16(ah, bh0, acc[g0], 0, 0, 0);
        acc[g1] = __builtin_amdgcn_mfma_f32_32x32x16_bf16(ah, bh1, acc[g1], 0, 0, 0);
        acc[g0] = __builtin_amdgcn_mfma_f32_32x32x16_bf16(al, bh0, acc[g0], 0, 0, 0);
        acc[g1] = __builtin_amdgcn_mfma_f32_32x32x16_bf16(al, bh1, acc[g1], 0, 0, 0);
        acc[g0] = __builtin_amdgcn_mfma_f32_32x32x16_bf16(ah, bl0, acc[g0], 0, 0, 0);
        acc[g1] = __builtin_amdgcn_mfma_f32_32x32x16_bf16(ah, bl1, acc[g1], 0, 0, 0);
      }
    }
#pragma unroll
    for (int reg = 0; reg < 16; ++reg) {
      int row32 = (reg & 3) + ((reg >> 2) << 3) + (hs << 2);
      float ig = fast_sigmoid(acc[0][reg]);
      float fg = fast_sigmoid(acc[1][reg]);
      float gg = fast_tanh  (acc[2][reg]);
      float og = fast_sigmoid(acc[3][reg]);
      float c  = fmaf(fg, c_reg[reg], ig * gg);
      c_reg[reg] = c;
      float h  = og * fast_tanh(c);
      unsigned short hi, lo;
      split_trunc(h, hi, lo);
      hfh[nbuf][coff + row32 * 8] = hi;
      hfl[nbuf][coff + row32 * 8] = lo;
      if (t == NHIST - 1) {
        hout[(b0 + row32) * HH + col] = h;
        cout[(b0 + row32) * HH + col] = c;
      }
    }
    __syncthreads();
    buf = nbuf;
  }
}

// -------------------------------- MC kernel --------------------------------
// one kb slice of the gate matmul for one chain (12 MFMAs, ~1 L2 wait)
#define MM_KB(ACC, HFH_T, HFL, KB) {                                          \
    bfrag ah = *(const bfrag*)&HFH_T[(KB) * SKB + aoff];                      \
    bfrag al = *(const bfrag*)&HFL[(KB) * SKB + aoff];                        \
    _Pragma("unroll")                                                         \
    for (int gp = 0; gp < 2; ++gp) {                                          \
      const int g0 = 2 * gp, g1 = 2 * gp + 1;                                 \
      const int off0 = ((((g0 << 2) + cg) << 3) + (KB)) * 512 + lane * 8;     \
      const int off1 = ((((g1 << 2) + cg) << 3) + (KB)) * 512 + lane * 8;     \
      bfrag bh0 = *(const bfrag*)&Bhi[off0];                                  \
      bfrag bl0 = *(const bfrag*)&Blo[off0];                                  \
      bfrag bh1 = *(const bfrag*)&Bhi[off1];                                  \
      bfrag bl1 = *(const bfrag*)&Blo[off1];                                  \
      ACC[g0] = __builtin_amdgcn_mfma_f32_32x32x16_bf16(ah, bh0, ACC[g0], 0, 0, 0); \
      ACC[g1] = __builtin_amdgcn_mfma_f32_32x32x16_bf16(ah, bh1, ACC[g1], 0, 0, 0); \
      ACC[g0] = __builtin_amdgcn_mfma_f32_32x32x16_bf16(al, bh0, ACC[g0], 0, 0, 0); \
      ACC[g1] = __builtin_amdgcn_mfma_f32_32x32x16_bf16(al, bh1, ACC[g1], 0, 0, 0); \
      ACC[g0] = __builtin_amdgcn_mfma_f32_32x32x16_bf16(ah, bl0, ACC[g0], 0, 0, 0); \
      ACC[g1] = __builtin_amdgcn_mfma_f32_32x32x16_bf16(ah, bl1, ACC[g1], 0, 0, 0); \
    }                                                                         \
  }

// one register of the LSTM epilogue (gates + c/h update + frag store).
// REG must be a compile-time constant (ext_vector dynamic index -> scratch).
#define EPI_REG(ACC, CR, XS, HFH_N, HFL, REG) {                               \
    const int row32 = ((REG) & 3) + (((REG) >> 2) << 3) + (hs << 2);          \
    float xv = XS[row32];                                                     \
    float ig = fast_sigmoid(ACC[0][REG] + fmaf(xv, wih_r[0], bb_r[0]));       \
    float fg = fast_sigmoid(ACC[1][REG] + fmaf(xv, wih_r[1], bb_r[1]));       \
    float gg = fast_tanh  (ACC[2][REG] + fmaf(xv, wih_r[2], bb_r[2]));        \
    float og = fast_sigmoid(ACC[3][REG] + fmaf(xv, wih_r[3], bb_r[3]));       \
    float c  = fmaf(fg, CR[REG], ig * gg);                                    \
    CR[REG] = c;                                                              \
    float h  = og * fast_tanh(c);                                             \
    unsigned short hi_, lo_;                                                  \
    split_trunc(h, hi_, lo_);                                                 \
    HFH_N[coff + row32 * 8] = hi_;                                            \
    HFL[coff + row32 * 8] = lo_;                                              \
  }

// per-chain tail: mu/ls MFMA from h(TT+1), RNG, next x, logw update.
// Runs on one wave (caller guards); reads HFH_N (h at step TT+1).
#define TAIL(TT, HFH_N, MU_P, LS_P, X_P, S) {                                 \
    facc am;                                                                  \
    _Pragma("unroll")                                                         \
    for (int e = 0; e < 16; ++e) am[e] = 0.0f;                                \
    _Pragma("unroll 2")                                                       \
    for (int kb = 0; kb < 8; ++kb) {                                          \
      const bfrag bm = *(const bfrag*)&Bmu[kb * 512 + lane * 8];              \
      const bfrag a0 = *(const bfrag*)&HFH_N[kb * SKB + aoff];                \
      am = __builtin_amdgcn_mfma_f32_32x32x16_bf16(a0, bm, am, 0, 0, 0);      \
    }                                                                         \
    if (m < 2) {                                                              \
      float* dst = (m == 0) ? (MU_P) : (LS_P);                                \
      _Pragma("unroll")                                                       \
      for (int reg = 0; reg < 16; ++reg)                                      \
        dst[(reg & 3) + ((reg >> 2) << 3) + (hs << 2)] = am[reg];             \
    }                                                                         \
    float mu  = (MU_P)[m] + bmu;                                              \
    float lsc = fminf(fmaxf((LS_P)[m] + bls, -5.0f), 2.0f);                   \
    float sg  = __expf(lsc);                                                  \
    const int ko = 2 * ((S) * NSTEP + (TT));                                  \
    uint32_t k0 = keys[ko], k1 = keys[ko + 1];                                \
    float z  = normal32(k0, k1, (uint32_t)(b0 + m));                          \
    float xn = fmaf(sg, z + 0.5f, mu);                                        \
    logw -= fmaf(0.5f, z, 0.125f);                                            \
    if ((TT) == TCAP) outv = xn;                                              \
    if (lane < 32) (X_P)[lane] = xn;                                          \
  }

__launch_bounds__(256, 2)
__global__ void mc_kernel(const float* __restrict__ ret,
                          const float* __restrict__ W_ih,
                          const float* __restrict__ bias,
                          const unsigned short* __restrict__ Bhi,
                          const unsigned short* __restrict__ Blo,
                          const unsigned short* __restrict__ Bmu,
                          const float* __restrict__ hin,
                          const float* __restrict__ cin,
                          const float* __restrict__ b_mu,
                          const float* __restrict__ b_ls,
                          const uint32_t* __restrict__ keys,
                          float* __restrict__ accum) {
  __shared__ unsigned short hfhA[2][HFN];
  __shared__ unsigned short hflA[HFN];
  __shared__ unsigned short hfhB[2][HFN];
  __shared__ unsigned short hflB[HFN];
  __shared__ float x_sA[32], mu_sA[32], ls_sA[32];
  __shared__ float x_sB[32], mu_sB[32], ls_sB[32];

  const int tid  = threadIdx.x;
  const int lane = tid & 63;
  const int cg   = tid >> 6;
  const int hs   = lane >> 5;
  const int m    = lane & 31;
  const int col  = (cg << 5) + m;

  const int sp = blockIdx.x >> 8;
  const int b0 = (blockIdx.x & 255) << 5;
  const int sA = sp * 2, sB = sp * 2 + 1;

  float wih_r[4], bb_r[4];
#pragma unroll
  for (int gi = 0; gi < 4; ++gi) {
    wih_r[gi] = W_ih[(gi << 7) + col];
    bb_r[gi]  = bias[(gi << 7) + col];
  }
  const float bmu = b_mu[0], bls = b_ls[0];

  const int coff = (col >> 4) * SKB + ((col >> 3) & 1) * SHS + (col & 7);
  const int aoff = hs * SHS + m * 8;

  // init: both chains start from the same (h, c) per the reference
  float cA[16], cB[16];
#pragma unroll
  for (int reg = 0; reg < 16; ++reg) {
    int row32 = (reg & 3) + ((reg >> 2) << 3) + (hs << 2);
    int grow = b0 + row32;
    float hv = hin[grow * HH + col];
    float cv = cin[grow * HH + col];
    cA[reg] = cv; cB[reg] = cv;
    unsigned short hi, lo;
    split_trunc(hv, hi, lo);
    hfhA[0][coff + row32 * 8] = hi;
    hflA[coff + row32 * 8] = lo;
    hfhB[0][coff + row32 * 8] = hi;
    hflB[coff + row32 * 8] = lo;
  }
  if (tid < 32) {
    float xv = ret[126 * NB + b0 + tid];
    x_sA[tid] = xv; x_sB[tid] = xv;
  }
  float logw = 0.0f, outv = 0.0f;
  __syncthreads();

  // prologue: matmul A(0) from hfhA[0]/hflA
  facc accA[4], accB[4];
#pragma unroll
  for (int gi = 0; gi < 4; ++gi)
#pragma unroll
    for (int e = 0; e < 16; ++e) accA[gi][e] = 0.0f;
#pragma unroll 1
  for (int kb = 0; kb < 8; ++kb) {
    MM_KB(accA, hfhA[0], hflA, kb)
  }
  __syncthreads();   // prologue hflA/hfhA[0] reads done before epi A(0) writes

#pragma unroll 1
  for (int t = 0; t < NSTEP; ++t) {
    // ============ phase1: matmul B(t) + epilogue A(t); wave1: tail B(t-1)
    // mm-B reads hfhB[t&1]/hflB; epi-A consumes accA, writes hfhA[(t+1)&1]/hflA
#pragma unroll
    for (int gi = 0; gi < 4; ++gi)
#pragma unroll
      for (int e = 0; e < 16; ++e) accB[gi][e] = 0.0f;
    if (cg == 1 && t != 0) {
      TAIL(t - 1, hfhB[t & 1], mu_sB, ls_sB, x_sB, sB)
    }
#pragma unroll
    for (int kb = 0; kb < 8; ++kb) {
      MM_KB(accB, hfhB[t & 1], hflB, kb)
      EPI_REG(accA, cA, x_sA, hfhA[(t + 1) & 1], hflA, 2 * kb)
      EPI_REG(accA, cA, x_sA, hfhA[(t + 1) & 1], hflA, 2 * kb + 1)
    }
    __syncthreads();   // B1: epi-A writes + tail-B x_sB visible; mm-B reads done

    // ============ phase2: matmul A(t+1) + epilogue B(t); wave0: tail A(t)
    // mm-A reads hfhA[(t+1)&1]/hflA; epi-B writes hfhB[(t+1)&1]/hflB
#pragma unroll
    for (int gi = 0; gi < 4; ++gi)
#pragma unroll
      for (int e = 0; e < 16; ++e) accA[gi][e] = 0.0f;
    if (cg == 0) {
      TAIL(t, hfhA[(t + 1) & 1], mu_sA, ls_sA, x_sA, sA)
    }
    const bool mmA = (t < NSTEP - 1);
#pragma unroll
    for (int kb = 0; kb < 8; ++kb) {
      if (mmA) {
        MM_KB(accA, hfhA[(t + 1) & 1], hflA, kb)
      }
      EPI_REG(accB, cB, x_sB, hfhB[(t + 1) & 1], hflB, 2 * kb)
      EPI_REG(accB, cB, x_sB, hfhB[(t + 1) & 1], hflB, 2 * kb + 1)
    }
    __syncthreads();   // B2: epi-B writes + tail-A x_sA visible; mm-A/tail-A reads done
  }

  // post-loop: chain B's final tail (logw only; outv set at t==TCAP inside loop)
  if (cg == 1) {
    TAIL(NSTEP - 1, hfhB[0], mu_sB, ls_sB, x_sB, sB)
  }

  if (tid < 128 && lane < 32) {        // wave0 -> sample A, wave1 -> sample B
    float wt = __expf(logw);
    float ow = outv * wt;
    int b = b0 + lane;
    atomicAdd(&accum[0 * NB + b], wt);
    atomicAdd(&accum[1 * NB + b], ow);
    atomicAdd(&accum[2 * NB + b], wt * wt);
    atomicAdd(&accum[3 * NB + b], ow * ow);
    atomicAdd(&accum[4 * NB + b], outv * wt * wt);
  }
}

// ------------------------------- final kernel ------------------------------
__global__ void final_kernel(const float* __restrict__ accum,
                             float* __restrict__ out) {
  int b = blockIdx.x * blockDim.x + threadIdx.x;
  if (b >= NB) return;
  float sw  = accum[0 * NB + b];
  float sm1 = accum[1 * NB + b];
  float sqw = accum[2 * NB + b];
  float sm2 = accum[3 * NB + b];
  float shm = accum[4 * NB + b];
  float mean = sm1 / sw;
  float sem = sm2 + sqw * mean * mean - 2.0f * shm * mean;
  sem = sqrtf(sem / (float)(NSAMP * (NSAMP - 1)));
  out[b] = mean;
  out[NB + b] = sem;
}

// ------------------------------- launcher ----------------------------------
extern "C" void kernel_launch(void* const* d_in, const int* in_sizes, int n_in,
                              void* d_out, int out_size, void* d_ws, size_t ws_size,
                              hipStream_t stream) {
  (void)in_sizes; (void)n_in; (void)out_size; (void)ws_size;
  const float* inp  = (const float*)d_in[0];
  const float* pert = (const float*)d_in[1];
  const float* W_ih = (const float*)d_in[2];
  const float* W_hh = (const float*)d_in[3];
  const float* bias = (const float*)d_in[4];
  const float* w_mu = (const float*)d_in[5];
  const float* b_mu = (const float*)d_in[6];
  const float* w_ls = (const float*)d_in[7];
  const float* b_ls = (const float*)d_in[8];

  char* ws = (char*)d_ws;
  float* ret = (float*)ws;        ws += (size_t)NRET * NB * sizeof(float);
  float* hh  = (float*)ws;        ws += (size_t)NB * HH * sizeof(float);
  float* cc  = (float*)ws;        ws += (size_t)NB * HH * sizeof(float);
  uint32_t* keys = (uint32_t*)ws; ws += (size_t)NSAMP * NSTEP * 2 * sizeof(uint32_t);
  float* accum = (float*)ws;      ws += (size_t)5 * NB * sizeof(float);
  unsigned short* Bhi = (unsigned short*)ws; ws += 65536 * sizeof(unsigned short);
  unsigned short* Blo = (unsigned short*)ws; ws += 65536 * sizeof(unsigned short);
  unsigned short* Bmu = (unsigned short*)ws; ws += 4096 * sizeof(unsigned short);

  hipMemsetAsync(accum, 0, (size_t)5 * NB * sizeof(float), stream);
  returns_kernel<<<(NRET * NB + 255) / 256, 256, 0, stream>>>(inp, pert, ret);
  keys_kernel<<<(NSAMP * NSTEP + 255) / 256, 256, 0, stream>>>(keys);
  pack_kernel<<<(65536 + 4096) / 256, 256, 0, stream>>>(W_hh, w_mu, w_ls, Bhi, Blo, Bmu);
  hist_kernel<<<NB / 32, 256, 0, stream>>>(ret, W_ih, bias, Bhi, Blo, hh, cc);
  mc_kernel<<<(NSAMP / 2) * (NB / 32), 256, 0, stream>>>(ret, W_ih, bias, Bhi, Blo, Bmu,
      hh, cc, b_mu, b_ls, keys, accum);
  final_kernel<<<NB / 256, 256, 0, stream>>>(accum, (float*)d_out);
}

// Round 4
// 8006.727 us; speedup vs baseline: 4.4113x; 4.4113x over previous
//
#include <hip/hip_runtime.h>
#include <stdint.h>
#include <math.h>

// ---------------------------------------------------------------------------
// Round 21: R18 (verified 7988 us) + ONE change: mc_kernel kb-loop unroll 2.
// R19/R20 post-mortem: phase-overlap spilled (FETCH 50GB = scratch; R18 is
// at exactly 256 unified regs = the 2-waves/SIMD budget; accA live across
// barriers + accB matmul temps + interleaved epi/tail pushed past it with
// occupancy pinned -> allocator spilled). Lesson: zero headroom for
// cross-barrier acc liveness. Remaining R18 stall decomposition (7.7k-cyc
// step slot): 1536 MFMA, ~1.1k epi VALU, ~0.4k tail, ~0.5k barriers, and
// ~2.5k EXPOSED B-frag L2 latency from the unroll-1 kb loop (loads of kb+1
// can't issue under kb's MFMAs). unroll 2 doubles the body so the
// pressure-aware scheduler pipelines the load batches; +~16 transient regs
// fits the ~20-reg arch headroom without touching the 128-AGPR acc budget.
// ---------------------------------------------------------------------------

#define HH     128
#define NG     512
#define NB     8192
#define NSAMP  100
#define NSTEP  20
#define TCAP   18
#define NHIST  126
#define NRET   127

using bfrag = __attribute__((ext_vector_type(8))) short;   // 8 bf16 = 4 VGPRs
using facc  = __attribute__((ext_vector_type(16))) float;  // 16 f32 acc

// LDS frag strides (shorts): per-(kb,hs) region 264 (8 pad), per-kb 528.
#define SHS 264
#define SKB 528
#define HFN 4224   // 8 kb * 528

// ----------------------------- threefry2x32 --------------------------------
__device__ __forceinline__ void tf2x32(uint32_t k0, uint32_t k1,
                                       uint32_t x0, uint32_t x1,
                                       uint32_t &y0, uint32_t &y1) {
  uint32_t ks2 = k0 ^ k1 ^ 0x1BD11BDAu;
  x0 += k0; x1 += k1;
#define RR(r) { x0 += x1; x1 = (x1 << (r)) | (x1 >> (32 - (r))); x1 ^= x0; }
  RR(13) RR(15) RR(26) RR(6)   x0 += k1;  x1 += ks2 + 1u;
  RR(17) RR(29) RR(16) RR(24)  x0 += ks2; x1 += k0  + 2u;
  RR(13) RR(15) RR(26) RR(6)   x0 += k0;  x1 += k1  + 3u;
  RR(17) RR(29) RR(16) RR(24)  x0 += k1;  x1 += ks2 + 4u;
  RR(13) RR(15) RR(26) RR(6)   x0 += ks2; x1 += k0  + 5u;
#undef RR
  y0 = x0; y1 = x1;
}

__device__ __forceinline__ float erfinv32(float x) {
  float w = -__logf(fmaxf(1.0f - x * x, 1e-37f));
  float p;
  if (w < 5.0f) {
    w = w - 2.5f;
    p = 2.81022636e-08f;
    p = fmaf(p, w, 3.43273939e-07f);
    p = fmaf(p, w, -3.5233877e-06f);
    p = fmaf(p, w, -4.39150654e-06f);
    p = fmaf(p, w, 0.00021858087f);
    p = fmaf(p, w, -0.00125372503f);
    p = fmaf(p, w, -0.00417768164f);
    p = fmaf(p, w, 0.246640727f);
    p = fmaf(p, w, 1.50140941f);
  } else {
    w = sqrtf(w) - 3.0f;
    p = -0.000200214257f;
    p = fmaf(p, w, 0.000100950558f);
    p = fmaf(p, w, 0.00134934322f);
    p = fmaf(p, w, -0.00367342844f);
    p = fmaf(p, w, 0.00573950773f);
    p = fmaf(p, w, -0.0076224613f);
    p = fmaf(p, w, 0.00943887047f);
    p = fmaf(p, w, 1.00167406f);
    p = fmaf(p, w, 2.83297682f);
  }
  return p * x;
}

__device__ __forceinline__ float normal32(uint32_t k0, uint32_t k1, uint32_t idx) {
  uint32_t y0, y1;
  tf2x32(k0, k1, 0u, idx, y0, y1);
  uint32_t bits = y0 ^ y1;
  float f = __uint_as_float((bits >> 9) | 0x3f800000u) - 1.0f;
  const float lo = __uint_as_float(0xBF7FFFFFu);
  float u = fmaxf(lo, f * 2.0f + lo);
  return 1.41421356f * erfinv32(u);
}

__device__ __forceinline__ float fast_sigmoid(float x) {
  return __builtin_amdgcn_rcpf(1.0f + __expf(-x));
}
__device__ __forceinline__ float fast_tanh(float x) {
  return 1.0f - 2.0f * __builtin_amdgcn_rcpf(1.0f + __expf(2.0f * x));
}

// RNE bf16 (one-time B pack only)
__device__ __forceinline__ unsigned short f2bf(float x) {
  uint32_t u = __float_as_uint(x);
  uint32_t r = u + 0x7fffu + ((u >> 16) & 1u);
  return (unsigned short)(r >> 16);
}
__device__ __forceinline__ float bf2f(unsigned short h) {
  return __uint_as_float(((uint32_t)h) << 16);
}

// truncation split: hi = top16(h); lo = top16(h - hi) (Sterbenz-exact sub)
__device__ __forceinline__ void split_trunc(float h, unsigned short &hi,
                                            unsigned short &lo) {
  uint32_t u = __float_as_uint(h);
  hi = (unsigned short)(u >> 16);
  float hv = __uint_as_float(u & 0xFFFF0000u);
  lo = (unsigned short)(__float_as_uint(h - hv) >> 16);
}

// ------------------------------- small kernels -----------------------------
__global__ void returns_kernel(const float* __restrict__ inp,
                               const float* __restrict__ pert,
                               float* __restrict__ ret) {
  int i = blockIdx.x * blockDim.x + threadIdx.x;
  if (i >= NRET * NB) return;
  int s = i / NB, b = i - s * NB;
  float p0 = inp[s * NB + b] * (1.0f + pert[s * NB + b]);
  float p1 = inp[(s + 1) * NB + b] * (1.0f + pert[(s + 1) * NB + b]);
  ret[i] = p1 - p0;
}

__global__ void keys_kernel(uint32_t* __restrict__ keys) {
  int id = blockIdx.x * blockDim.x + threadIdx.x;
  if (id >= NSAMP * NSTEP) return;
  int s = id / NSTEP, t = id - s * NSTEP;
  uint32_t sk0, sk1, k0, k1;
  tf2x32(0u, 42u, 0u, (uint32_t)s, sk0, sk1);
  tf2x32(sk0, sk1, 0u, (uint32_t)t, k0, k1);
  keys[2 * id] = k0; keys[2 * id + 1] = k1;
}

// B-fragment pack (RNE): Bhi/Blo[((gct*8+kb)*64+lane)*8+j]
__global__ void pack_kernel(const float* __restrict__ W_hh,
                            const float* __restrict__ w_mu,
                            const float* __restrict__ w_ls,
                            unsigned short* __restrict__ Bhi,
                            unsigned short* __restrict__ Blo,
                            unsigned short* __restrict__ Bmu) {
  int idx = blockIdx.x * blockDim.x + threadIdx.x;
  if (idx < 65536) {
    int j = idx & 7, lane = (idx >> 3) & 63, kb = (idx >> 9) & 7, gct = idx >> 12;
    int k = kb * 16 + ((lane >> 5) << 3) + j;
    int g = (gct << 5) + (lane & 31);
    float w = W_hh[k * NG + g];
    unsigned short hi = f2bf(w);
    unsigned short lo = f2bf(w - bf2f(hi));
    Bhi[idx] = hi; Blo[idx] = lo;
  } else if (idx < 65536 + 4096) {
    int i2 = idx - 65536;
    int j = i2 & 7, lane = (i2 >> 3) & 63, kb = (i2 >> 9) & 7;
    int k = kb * 16 + ((lane >> 5) << 3) + j;
    int col = lane & 31;
    float v = (col == 0) ? w_mu[k] : (col == 1 ? w_ls[k] : 0.0f);
    Bmu[i2] = f2bf(v);
  }
}

// ------------------------------ history kernel -----------------------------
__launch_bounds__(256, 1)
__global__ void hist_kernel(const float* __restrict__ ret,
                            const float* __restrict__ W_ih,
                            const float* __restrict__ bias,
                            const unsigned short* __restrict__ Bhi,
                            const unsigned short* __restrict__ Blo,
                            float* __restrict__ hout,
                            float* __restrict__ cout) {
  __shared__ unsigned short hfh[2][HFN];
  __shared__ unsigned short hfl[2][HFN];

  const int tid  = threadIdx.x;
  const int lane = tid & 63;
  const int cg   = tid >> 6;
  const int hs   = lane >> 5;
  const int m    = lane & 31;
  const int col  = (cg << 5) + m;
  const int b0   = blockIdx.x << 5;

  float wih_r[4], bb_r[4];
#pragma unroll
  for (int gi = 0; gi < 4; ++gi) {
    wih_r[gi] = W_ih[(gi << 7) + col];
    bb_r[gi]  = bias[(gi << 7) + col];
  }

  const int coff = (col >> 4) * SKB + ((col >> 3) & 1) * SHS + (col & 7);
  const int aoff = hs * SHS + m * 8;

  float c_reg[16];
#pragma unroll
  for (int reg = 0; reg < 16; ++reg) {
    int row32 = (reg & 3) + ((reg >> 2) << 3) + (hs << 2);
    c_reg[reg] = 0.0f;
    hfh[0][coff + row32 * 8] = 0;
    hfl[0][coff + row32 * 8] = 0;
  }
  __syncthreads();

  int buf = 0;
#pragma unroll 1
  for (int t = 0; t < NHIST; ++t) {
    const int nbuf = buf ^ 1;
    facc acc[4];
#pragma unroll
    for (int reg = 0; reg < 16; ++reg) {
      int row32 = (reg & 3) + ((reg >> 2) << 3) + (hs << 2);
      float xv = ret[t * NB + b0 + row32];
#pragma unroll
      for (int gi = 0; gi < 4; ++gi)
        acc[gi][reg] = fmaf(xv, wih_r[gi], bb_r[gi]);
    }
#pragma unroll 1
    for (int kb = 0; kb < 8; ++kb) {
      bfrag ah = *(const bfrag*)&hfh[buf][kb * SKB + aoff];
      bfrag al = *(const bfrag*)&hfl[buf][kb * SKB + aoff];
#pragma unroll
      for (int gp = 0; gp < 2; ++gp) {
        const int g0 = 2 * gp, g1 = 2 * gp + 1;
        const int off0 = ((((g0 << 2) + cg) << 3) + kb) * 512 + lane * 8;
        const int off1 = ((((g1 << 2) + cg) << 3) + kb) * 512 + lane * 8;
        bfrag bh0 = *(const bfrag*)&Bhi[off0];
        bfrag bl0 = *(const bfrag*)&Blo[off0];
        bfrag bh1 = *(const bfrag*)&Bhi[off1];
        bfrag bl1 = *(const bfrag*)&Blo[off1];
        acc[g0] = __builtin_amdgcn_mfma_f32_32x32x16_bf16(ah, bh0, acc[g0], 0, 0, 0);
        acc[g1] = __builtin_amdgcn_mfma_f32_32x32x16_bf16(ah, bh1, acc[g1], 0, 0, 0);
        acc[g0] = __builtin_amdgcn_mfma_f32_32x32x16_bf16(al, bh0, acc[g0], 0, 0, 0);
        acc[g1] = __builtin_amdgcn_mfma_f32_32x32x16_bf16(al, bh1, acc[g1], 0, 0, 0);
        acc[g0] = __builtin_amdgcn_mfma_f32_32x32x16_bf16(ah, bl0, acc[g0], 0, 0, 0);
        acc[g1] = __builtin_amdgcn_mfma_f32_32x32x16_bf16(ah, bl1, acc[g1], 0, 0, 0);
      }
    }
#pragma unroll
    for (int reg = 0; reg < 16; ++reg) {
      int row32 = (reg & 3) + ((reg >> 2) << 3) + (hs << 2);
      float ig = fast_sigmoid(acc[0][reg]);
      float fg = fast_sigmoid(acc[1][reg]);
      float gg = fast_tanh  (acc[2][reg]);
      float og = fast_sigmoid(acc[3][reg]);
      float c  = fmaf(fg, c_reg[reg], ig * gg);
      c_reg[reg] = c;
      float h  = og * fast_tanh(c);
      unsigned short hi, lo;
      split_trunc(h, hi, lo);
      hfh[nbuf][coff + row32 * 8] = hi;
      hfl[nbuf][coff + row32 * 8] = lo;
      if (t == NHIST - 1) {
        hout[(b0 + row32) * HH + col] = h;
        cout[(b0 + row32) * HH + col] = c;
      }
    }
    __syncthreads();
    buf = nbuf;
  }
}

// -------------------------------- MC kernel --------------------------------
// Dual-chain: one block advances samples sA=2*sp and sB=2*sp+1 for the same
// 32-row batch chunk. B fragments are loaded once per kb and feed both
// chains' MFMAs (24 per kb). Wave0 runs chain-A tail, wave1 chain-B tail.
__launch_bounds__(256, 2)
__global__ void mc_kernel(const float* __restrict__ ret,
                          const float* __restrict__ W_ih,
                          const float* __restrict__ bias,
                          const unsigned short* __restrict__ Bhi,
                          const unsigned short* __restrict__ Blo,
                          const unsigned short* __restrict__ Bmu,
                          const float* __restrict__ hin,
                          const float* __restrict__ cin,
                          const float* __restrict__ b_mu,
                          const float* __restrict__ b_ls,
                          const uint32_t* __restrict__ keys,
                          float* __restrict__ accum) {
  __shared__ unsigned short hfhA[2][HFN];
  __shared__ unsigned short hflA[HFN];
  __shared__ unsigned short hfhB[2][HFN];
  __shared__ unsigned short hflB[HFN];
  __shared__ float x_sA[32], mu_sA[32], ls_sA[32];
  __shared__ float x_sB[32], mu_sB[32], ls_sB[32];

  const int tid  = threadIdx.x;
  const int lane = tid & 63;
  const int cg   = tid >> 6;
  const int hs   = lane >> 5;
  const int m    = lane & 31;
  const int col  = (cg << 5) + m;

  const int sp = blockIdx.x >> 8;
  const int b0 = (blockIdx.x & 255) << 5;
  const int sA = sp * 2, sB = sp * 2 + 1;

  float wih_r[4], bb_r[4];
#pragma unroll
  for (int gi = 0; gi < 4; ++gi) {
    wih_r[gi] = W_ih[(gi << 7) + col];
    bb_r[gi]  = bias[(gi << 7) + col];
  }
  const float bmu = b_mu[0], bls = b_ls[0];

  const int coff = (col >> 4) * SKB + ((col >> 3) & 1) * SHS + (col & 7);
  const int aoff = hs * SHS + m * 8;

  // init: both chains start from the same (h, c) per the reference
  float cA[16], cB[16];
#pragma unroll
  for (int reg = 0; reg < 16; ++reg) {
    int row32 = (reg & 3) + ((reg >> 2) << 3) + (hs << 2);
    int grow = b0 + row32;
    float hv = hin[grow * HH + col];
    float cv = cin[grow * HH + col];
    cA[reg] = cv; cB[reg] = cv;
    unsigned short hi, lo;
    split_trunc(hv, hi, lo);
    hfhA[0][coff + row32 * 8] = hi;
    hflA[coff + row32 * 8] = lo;
    hfhB[0][coff + row32 * 8] = hi;
    hflB[coff + row32 * 8] = lo;
  }
  if (tid < 32) {
    float xv = ret[126 * NB + b0 + tid];
    x_sA[tid] = xv; x_sB[tid] = xv;
  }
  float logw = 0.0f, outv = 0.0f;
  __syncthreads();

  int buf = 0;
#pragma unroll 1
  for (int t = 0; t < NSTEP; ++t) {
    const int nbuf = buf ^ 1;

    // ---- fused gate matmul for both chains; each B frag feeds 24 MFMAs.
    // unroll 2: lets the scheduler issue kb+1's load batch under kb's MFMAs
    // (the only change vs R18 -- hides ~150-300cyc L2 latency per kb).
    facc accA[4], accB[4];
#pragma unroll
    for (int gi = 0; gi < 4; ++gi)
#pragma unroll
      for (int e = 0; e < 16; ++e) { accA[gi][e] = 0.0f; accB[gi][e] = 0.0f; }
#pragma unroll 2
    for (int kb = 0; kb < 8; ++kb) {
      bfrag ahA = *(const bfrag*)&hfhA[buf][kb * SKB + aoff];
      bfrag alA = *(const bfrag*)&hflA[kb * SKB + aoff];
      bfrag ahB = *(const bfrag*)&hfhB[buf][kb * SKB + aoff];
      bfrag alB = *(const bfrag*)&hflB[kb * SKB + aoff];
#pragma unroll
      for (int gp = 0; gp < 2; ++gp) {
        const int g0 = 2 * gp, g1 = 2 * gp + 1;
        const int off0 = ((((g0 << 2) + cg) << 3) + kb) * 512 + lane * 8;
        const int off1 = ((((g1 << 2) + cg) << 3) + kb) * 512 + lane * 8;
        bfrag bh0 = *(const bfrag*)&Bhi[off0];
        bfrag bl0 = *(const bfrag*)&Blo[off0];
        bfrag bh1 = *(const bfrag*)&Bhi[off1];
        bfrag bl1 = *(const bfrag*)&Blo[off1];
        accA[g0] = __builtin_amdgcn_mfma_f32_32x32x16_bf16(ahA, bh0, accA[g0], 0, 0, 0);
        accB[g0] = __builtin_amdgcn_mfma_f32_32x32x16_bf16(ahB, bh0, accB[g0], 0, 0, 0);
        accA[g1] = __builtin_amdgcn_mfma_f32_32x32x16_bf16(ahA, bh1, accA[g1], 0, 0, 0);
        accB[g1] = __builtin_amdgcn_mfma_f32_32x32x16_bf16(ahB, bh1, accB[g1], 0, 0, 0);
        accA[g0] = __builtin_amdgcn_mfma_f32_32x32x16_bf16(alA, bh0, accA[g0], 0, 0, 0);
        accB[g0] = __builtin_amdgcn_mfma_f32_32x32x16_bf16(alB, bh0, accB[g0], 0, 0, 0);
        accA[g1] = __builtin_amdgcn_mfma_f32_32x32x16_bf16(alA, bh1, accA[g1], 0, 0, 0);
        accB[g1] = __builtin_amdgcn_mfma_f32_32x32x16_bf16(alB, bh1, accB[g1], 0, 0, 0);
        accA[g0] = __builtin_amdgcn_mfma_f32_32x32x16_bf16(ahA, bl0, accA[g0], 0, 0, 0);
        accB[g0] = __builtin_amdgcn_mfma_f32_32x32x16_bf16(ahB, bl0, accB[g0], 0, 0, 0);
        accA[g1] = __builtin_amdgcn_mfma_f32_32x32x16_bf16(ahA, bl1, accA[g1], 0, 0, 0);
        accB[g1] = __builtin_amdgcn_mfma_f32_32x32x16_bf16(ahB, bl1, accB[g1], 0, 0, 0);
      }
    }
    __syncthreads();   // B1: hf* reads done; x_s*(t) visible

    // ---- epilogue chain A
#pragma unroll
    for (int reg = 0; reg < 16; ++reg) {
      int row32 = (reg & 3) + ((reg >> 2) << 3) + (hs << 2);
      float xv = x_sA[row32];
      float ig = fast_sigmoid(accA[0][reg] + fmaf(xv, wih_r[0], bb_r[0]));
      float fg = fast_sigmoid(accA[1][reg] + fmaf(xv, wih_r[1], bb_r[1]));
      float gg = fast_tanh  (accA[2][reg] + fmaf(xv, wih_r[2], bb_r[2]));
      float og = fast_sigmoid(accA[3][reg] + fmaf(xv, wih_r[3], bb_r[3]));
      float c  = fmaf(fg, cA[reg], ig * gg);
      cA[reg] = c;
      float h  = og * fast_tanh(c);
      unsigned short hi, lo;
      split_trunc(h, hi, lo);
      hfhA[nbuf][coff + row32 * 8] = hi;
      hflA[coff + row32 * 8] = lo;
    }
    // ---- epilogue chain B
#pragma unroll
    for (int reg = 0; reg < 16; ++reg) {
      int row32 = (reg & 3) + ((reg >> 2) << 3) + (hs << 2);
      float xv = x_sB[row32];
      float ig = fast_sigmoid(accB[0][reg] + fmaf(xv, wih_r[0], bb_r[0]));
      float fg = fast_sigmoid(accB[1][reg] + fmaf(xv, wih_r[1], bb_r[1]));
      float gg = fast_tanh  (accB[2][reg] + fmaf(xv, wih_r[2], bb_r[2]));
      float og = fast_sigmoid(accB[3][reg] + fmaf(xv, wih_r[3], bb_r[3]));
      float c  = fmaf(fg, cB[reg], ig * gg);
      cB[reg] = c;
      float h  = og * fast_tanh(c);
      unsigned short hi, lo;
      split_trunc(h, hi, lo);
      hfhB[nbuf][coff + row32 * 8] = hi;
      hflB[coff + row32 * 8] = lo;
    }
    __syncthreads();   // B2: h(t+1) frags visible for both chains

    if (tid < 128) {   // wave0: chain A tail; wave1: chain B tail
      const unsigned short* hfn;
      float *mu_p, *ls_p, *x_p;
      int s;
      if (tid < 64) { hfn = hfhA[nbuf]; mu_p = mu_sA; ls_p = ls_sA; x_p = x_sA; s = sA; }
      else          { hfn = hfhB[nbuf]; mu_p = mu_sB; ls_p = ls_sB; x_p = x_sB; s = sB; }
      facc am;
#pragma unroll
      for (int e = 0; e < 16; ++e) am[e] = 0.0f;
#pragma unroll 2
      for (int kb = 0; kb < 8; ++kb) {
        const bfrag bm = *(const bfrag*)&Bmu[kb * 512 + lane * 8];
        const bfrag a0 = *(const bfrag*)&hfn[kb * SKB + aoff];
        am = __builtin_amdgcn_mfma_f32_32x32x16_bf16(a0, bm, am, 0, 0, 0);
      }
      if (m < 2) {
        float* dst = (m == 0) ? mu_p : ls_p;
#pragma unroll
        for (int reg = 0; reg < 16; ++reg)
          dst[(reg & 3) + ((reg >> 2) << 3) + (hs << 2)] = am[reg];
      }
      // same-wave LDS RAW: compiler inserts lgkmcnt wait
      float mu  = mu_p[m] + bmu;
      float lsc = fminf(fmaxf(ls_p[m] + bls, -5.0f), 2.0f);
      float sg  = __expf(lsc);
      const int ko = 2 * (s * NSTEP + t);
      uint32_t k0 = keys[ko];
      uint32_t k1 = keys[ko + 1];
      float z  = normal32(k0, k1, (uint32_t)(b0 + m));
      float xn = fmaf(sg, z + 0.5f, mu);
      logw -= fmaf(0.5f, z, 0.125f);
      if (t == TCAP) outv = xn;
      if (lane < 32) x_p[lane] = xn;   // visible to consumers via next B1
    }
    buf = nbuf;
  }

  if (tid < 128 && lane < 32) {        // wave0 -> sample A, wave1 -> sample B
    float wt = __expf(logw);
    float ow = outv * wt;
    int b = b0 + lane;
    atomicAdd(&accum[0 * NB + b], wt);
    atomicAdd(&accum[1 * NB + b], ow);
    atomicAdd(&accum[2 * NB + b], wt * wt);
    atomicAdd(&accum[3 * NB + b], ow * ow);
    atomicAdd(&accum[4 * NB + b], outv * wt * wt);
  }
}

// ------------------------------- final kernel ------------------------------
__global__ void final_kernel(const float* __restrict__ accum,
                             float* __restrict__ out) {
  int b = blockIdx.x * blockDim.x + threadIdx.x;
  if (b >= NB) return;
  float sw  = accum[0 * NB + b];
  float sm1 = accum[1 * NB + b];
  float sqw = accum[2 * NB + b];
  float sm2 = accum[3 * NB + b];
  float shm = accum[4 * NB + b];
  float mean = sm1 / sw;
  float sem = sm2 + sqw * mean * mean - 2.0f * shm * mean;
  sem = sqrtf(sem / (float)(NSAMP * (NSAMP - 1)));
  out[b] = mean;
  out[NB + b] = sem;
}

// ------------------------------- launcher ----------------------------------
extern "C" void kernel_launch(void* const* d_in, const int* in_sizes, int n_in,
                              void* d_out, int out_size, void* d_ws, size_t ws_size,
                              hipStream_t stream) {
  (void)in_sizes; (void)n_in; (void)out_size; (void)ws_size;
  const float* inp  = (const float*)d_in[0];
  const float* pert = (const float*)d_in[1];
  const float* W_ih = (const float*)d_in[2];
  const float* W_hh = (const float*)d_in[3];
  const float* bias = (const float*)d_in[4];
  const float* w_mu = (const float*)d_in[5];
  const float* b_mu = (const float*)d_in[6];
  const float* w_ls = (const float*)d_in[7];
  const float* b_ls = (const float*)d_in[8];

  char* ws = (char*)d_ws;
  float* ret = (float*)ws;        ws += (size_t)NRET * NB * sizeof(float);
  float* hh  = (float*)ws;        ws += (size_t)NB * HH * sizeof(float);
  float* cc  = (float*)ws;        ws += (size_t)NB * HH * sizeof(float);
  uint32_t* keys = (uint32_t*)ws; ws += (size_t)NSAMP * NSTEP * 2 * sizeof(uint32_t);
  float* accum = (float*)ws;      ws += (size_t)5 * NB * sizeof(float);
  unsigned short* Bhi = (unsigned short*)ws; ws += 65536 * sizeof(unsigned short);
  unsigned short* Blo = (unsigned short*)ws; ws += 65536 * sizeof(unsigned short);
  unsigned short* Bmu = (unsigned short*)ws; ws += 4096 * sizeof(unsigned short);

  hipMemsetAsync(accum, 0, (size_t)5 * NB * sizeof(float), stream);
  returns_kernel<<<(NRET * NB + 255) / 256, 256, 0, stream>>>(inp, pert, ret);
  keys_kernel<<<(NSAMP * NSTEP + 255) / 256, 256, 0, stream>>>(keys);
  pack_kernel<<<(65536 + 4096) / 256, 256, 0, stream>>>(W_hh, w_mu, w_ls, Bhi, Blo, Bmu);
  hist_kernel<<<NB / 32, 256, 0, stream>>>(ret, W_ih, bias, Bhi, Blo, hh, cc);
  mc_kernel<<<(NSAMP / 2) * (NB / 32), 256, 0, stream>>>(ret, W_ih, bias, Bhi, Blo, Bmu,
      hh, cc, b_mu, b_ls, keys, accum);
  final_kernel<<<NB / 256, 256, 0, stream>>>(accum, (float*)d_out);
}

// Round 5
// 7661.756 us; speedup vs baseline: 4.6099x; 1.0450x over previous
//
#include <hip/hip_runtime.h>
#include <stdint.h>
#include <math.h>

// ---------------------------------------------------------------------------
// Round 22: TRANSCENDENTAL DIET on R21 (8006 us; R18/R21 statistically
// identical). Occupancy model corrected: unified pool = 512 regs/SIMD ->
// waves/SIMD = floor(512/regs); dual-chain = 256 regs = 2 waves/SIMD, hard.
// All occupancy escapes are blocked (128 acc/thread invariant at 256 thr).
// Remaining reducible pipe: epilogue transcendentals (10 trans/elem @ 8cyc).
// Changes (exact algebra, no structure/pressure change):
//  1) per-gate pre-scale of W_hh/W_ih/bias by {-L,-L,+2L,-L}, L=log2(e), so
//     exp2 applies directly to gate values (kills 4 preamble muls/elem).
//  2) merged activations: sig(i)*tanh(g) = (Eg-1)/((1+Ei)(1+Eg)), and
//     sig(o)*tanh(c') likewise -> 10 trans -> 8 trans per element.
//     Overflow guard: clamp tanh-side exp2 inputs at 80 (else inf*0=NaN).
// Applied to both hist_kernel and mc_kernel epilogues.
// ---------------------------------------------------------------------------

#define HH     128
#define NG     512
#define NB     8192
#define NSAMP  100
#define NSTEP  20
#define TCAP   18
#define NHIST  126
#define NRET   127

#define L2E  1.44269504f
#define L2E2 2.88539008f

using bfrag = __attribute__((ext_vector_type(8))) short;   // 8 bf16 = 4 VGPRs
using facc  = __attribute__((ext_vector_type(16))) float;  // 16 f32 acc

// LDS frag strides (shorts): per-(kb,hs) region 264 (8 pad), per-kb 528.
#define SHS 264
#define SKB 528
#define HFN 4224   // 8 kb * 528

// ----------------------------- threefry2x32 --------------------------------
__device__ __forceinline__ void tf2x32(uint32_t k0, uint32_t k1,
                                       uint32_t x0, uint32_t x1,
                                       uint32_t &y0, uint32_t &y1) {
  uint32_t ks2 = k0 ^ k1 ^ 0x1BD11BDAu;
  x0 += k0; x1 += k1;
#define RR(r) { x0 += x1; x1 = (x1 << (r)) | (x1 >> (32 - (r))); x1 ^= x0; }
  RR(13) RR(15) RR(26) RR(6)   x0 += k1;  x1 += ks2 + 1u;
  RR(17) RR(29) RR(16) RR(24)  x0 += ks2; x1 += k0  + 2u;
  RR(13) RR(15) RR(26) RR(6)   x0 += k0;  x1 += k1  + 3u;
  RR(17) RR(29) RR(16) RR(24)  x0 += k1;  x1 += ks2 + 4u;
  RR(13) RR(15) RR(26) RR(6)   x0 += ks2; x1 += k0  + 5u;
#undef RR
  y0 = x0; y1 = x1;
}

__device__ __forceinline__ float erfinv32(float x) {
  float w = -__logf(fmaxf(1.0f - x * x, 1e-37f));
  float p;
  if (w < 5.0f) {
    w = w - 2.5f;
    p = 2.81022636e-08f;
    p = fmaf(p, w, 3.43273939e-07f);
    p = fmaf(p, w, -3.5233877e-06f);
    p = fmaf(p, w, -4.39150654e-06f);
    p = fmaf(p, w, 0.00021858087f);
    p = fmaf(p, w, -0.00125372503f);
    p = fmaf(p, w, -0.00417768164f);
    p = fmaf(p, w, 0.246640727f);
    p = fmaf(p, w, 1.50140941f);
  } else {
    w = sqrtf(w) - 3.0f;
    p = -0.000200214257f;
    p = fmaf(p, w, 0.000100950558f);
    p = fmaf(p, w, 0.00134934322f);
    p = fmaf(p, w, -0.00367342844f);
    p = fmaf(p, w, 0.00573950773f);
    p = fmaf(p, w, -0.0076224613f);
    p = fmaf(p, w, 0.00943887047f);
    p = fmaf(p, w, 1.00167406f);
    p = fmaf(p, w, 2.83297682f);
  }
  return p * x;
}

__device__ __forceinline__ float normal32(uint32_t k0, uint32_t k1, uint32_t idx) {
  uint32_t y0, y1;
  tf2x32(k0, k1, 0u, idx, y0, y1);
  uint32_t bits = y0 ^ y1;
  float f = __uint_as_float((bits >> 9) | 0x3f800000u) - 1.0f;
  const float lo = __uint_as_float(0xBF7FFFFFu);
  float u = fmaxf(lo, f * 2.0f + lo);
  return 1.41421356f * erfinv32(u);
}

// RNE bf16 (one-time B pack only)
__device__ __forceinline__ unsigned short f2bf(float x) {
  uint32_t u = __float_as_uint(x);
  uint32_t r = u + 0x7fffu + ((u >> 16) & 1u);
  return (unsigned short)(r >> 16);
}
__device__ __forceinline__ float bf2f(unsigned short h) {
  return __uint_as_float(((uint32_t)h) << 16);
}

// truncation split: hi = top16(h); lo = top16(h - hi) (Sterbenz-exact sub)
__device__ __forceinline__ void split_trunc(float h, unsigned short &hi,
                                            unsigned short &lo) {
  uint32_t u = __float_as_uint(h);
  hi = (unsigned short)(u >> 16);
  float hv = __uint_as_float(u & 0xFFFF0000u);
  lo = (unsigned short)(__float_as_uint(h - hv) >> 16);
}

// Merged LSTM activation core. Inputs are PRE-SCALED gate values:
//   yi = -L*i, yf = -L*f, yg = 2L*g, yo = -L*o   (L = log2 e)
// Computes c' = sig(f)*c + sig(i)*tanh(g), h = sig(o)*tanh(c').
// 5 exp2 + 3 rcp per element; saturation-safe via clamp on tanh-side exps.
__device__ __forceinline__ void lstm_act(float yi, float yf, float yg, float yo,
                                         float &c, float &h) {
  float Ei = __builtin_amdgcn_exp2f(yi);
  float Eg = __builtin_amdgcn_exp2f(fminf(yg, 80.0f));
  float Ef = __builtin_amdgcn_exp2f(yf);
  float Eo = __builtin_amdgcn_exp2f(yo);
  float P1 = (Eg - 1.0f) * __builtin_amdgcn_rcpf((1.0f + Ei) * (1.0f + Eg));
  c = fmaf(c, __builtin_amdgcn_rcpf(1.0f + Ef), P1);
  float Ec = __builtin_amdgcn_exp2f(fminf(L2E2 * c, 80.0f));
  h = (Ec - 1.0f) * __builtin_amdgcn_rcpf((1.0f + Eo) * (1.0f + Ec));
}

// ------------------------------- small kernels -----------------------------
__global__ void returns_kernel(const float* __restrict__ inp,
                               const float* __restrict__ pert,
                               float* __restrict__ ret) {
  int i = blockIdx.x * blockDim.x + threadIdx.x;
  if (i >= NRET * NB) return;
  int s = i / NB, b = i - s * NB;
  float p0 = inp[s * NB + b] * (1.0f + pert[s * NB + b]);
  float p1 = inp[(s + 1) * NB + b] * (1.0f + pert[(s + 1) * NB + b]);
  ret[i] = p1 - p0;
}

__global__ void keys_kernel(uint32_t* __restrict__ keys) {
  int id = blockIdx.x * blockDim.x + threadIdx.x;
  if (id >= NSAMP * NSTEP) return;
  int s = id / NSTEP, t = id - s * NSTEP;
  uint32_t sk0, sk1, k0, k1;
  tf2x32(0u, 42u, 0u, (uint32_t)s, sk0, sk1);
  tf2x32(sk0, sk1, 0u, (uint32_t)t, k0, k1);
  keys[2 * id] = k0; keys[2 * id + 1] = k1;
}

// B-fragment pack (RNE): Bhi/Blo[((gct*8+kb)*64+lane)*8+j]
// W_hh is PRE-SCALED per gate: gates i,f,o by -L, gate g by +2L (exact
// linear transform so exp2 applies directly to the MFMA output).
__global__ void pack_kernel(const float* __restrict__ W_hh,
                            const float* __restrict__ w_mu,
                            const float* __restrict__ w_ls,
                            unsigned short* __restrict__ Bhi,
                            unsigned short* __restrict__ Blo,
                            unsigned short* __restrict__ Bmu) {
  int idx = blockIdx.x * blockDim.x + threadIdx.x;
  if (idx < 65536) {
    int j = idx & 7, lane = (idx >> 3) & 63, kb = (idx >> 9) & 7, gct = idx >> 12;
    int k = kb * 16 + ((lane >> 5) << 3) + j;
    int g = (gct << 5) + (lane & 31);
    float sc = ((gct >> 2) == 2) ? L2E2 : -L2E;
    float w = W_hh[k * NG + g] * sc;
    unsigned short hi = f2bf(w);
    unsigned short lo = f2bf(w - bf2f(hi));
    Bhi[idx] = hi; Blo[idx] = lo;
  } else if (idx < 65536 + 4096) {
    int i2 = idx - 65536;
    int j = i2 & 7, lane = (i2 >> 3) & 63, kb = (i2 >> 9) & 7;
    int k = kb * 16 + ((lane >> 5) << 3) + j;
    int col = lane & 31;
    float v = (col == 0) ? w_mu[k] : (col == 1 ? w_ls[k] : 0.0f);
    Bmu[i2] = f2bf(v);
  }
}

// ------------------------------ history kernel -----------------------------
__launch_bounds__(256, 1)
__global__ void hist_kernel(const float* __restrict__ ret,
                            const float* __restrict__ W_ih,
                            const float* __restrict__ bias,
                            const unsigned short* __restrict__ Bhi,
                            const unsigned short* __restrict__ Blo,
                            float* __restrict__ hout,
                            float* __restrict__ cout) {
  __shared__ unsigned short hfh[2][HFN];
  __shared__ unsigned short hfl[2][HFN];

  const int tid  = threadIdx.x;
  const int lane = tid & 63;
  const int cg   = tid >> 6;
  const int hs   = lane >> 5;
  const int m    = lane & 31;
  const int col  = (cg << 5) + m;
  const int b0   = blockIdx.x << 5;

  float wih_r[4], bb_r[4];
#pragma unroll
  for (int gi = 0; gi < 4; ++gi) {
    float sc = (gi == 2) ? L2E2 : -L2E;
    wih_r[gi] = W_ih[(gi << 7) + col] * sc;
    bb_r[gi]  = bias[(gi << 7) + col] * sc;
  }

  const int coff = (col >> 4) * SKB + ((col >> 3) & 1) * SHS + (col & 7);
  const int aoff = hs * SHS + m * 8;

  float c_reg[16];
#pragma unroll
  for (int reg = 0; reg < 16; ++reg) {
    int row32 = (reg & 3) + ((reg >> 2) << 3) + (hs << 2);
    c_reg[reg] = 0.0f;
    hfh[0][coff + row32 * 8] = 0;
    hfl[0][coff + row32 * 8] = 0;
  }
  __syncthreads();

  int buf = 0;
#pragma unroll 1
  for (int t = 0; t < NHIST; ++t) {
    const int nbuf = buf ^ 1;
    facc acc[4];
#pragma unroll
    for (int reg = 0; reg < 16; ++reg) {
      int row32 = (reg & 3) + ((reg >> 2) << 3) + (hs << 2);
      float xv = ret[t * NB + b0 + row32];
#pragma unroll
      for (int gi = 0; gi < 4; ++gi)
        acc[gi][reg] = fmaf(xv, wih_r[gi], bb_r[gi]);
    }
#pragma unroll 1
    for (int kb = 0; kb < 8; ++kb) {
      bfrag ah = *(const bfrag*)&hfh[buf][kb * SKB + aoff];
      bfrag al = *(const bfrag*)&hfl[buf][kb * SKB + aoff];
#pragma unroll
      for (int gp = 0; gp < 2; ++gp) {
        const int g0 = 2 * gp, g1 = 2 * gp + 1;
        const int off0 = ((((g0 << 2) + cg) << 3) + kb) * 512 + lane * 8;
        const int off1 = ((((g1 << 2) + cg) << 3) + kb) * 512 + lane * 8;
        bfrag bh0 = *(const bfrag*)&Bhi[off0];
        bfrag bl0 = *(const bfrag*)&Blo[off0];
        bfrag bh1 = *(const bfrag*)&Bhi[off1];
        bfrag bl1 = *(const bfrag*)&Blo[off1];
        acc[g0] = __builtin_amdgcn_mfma_f32_32x32x16_bf16(ah, bh0, acc[g0], 0, 0, 0);
        acc[g1] = __builtin_amdgcn_mfma_f32_32x32x16_bf16(ah, bh1, acc[g1], 0, 0, 0);
        acc[g0] = __builtin_amdgcn_mfma_f32_32x32x16_bf16(al, bh0, acc[g0], 0, 0, 0);
        acc[g1] = __builtin_amdgcn_mfma_f32_32x32x16_bf16(al, bh1, acc[g1], 0, 0, 0);
        acc[g0] = __builtin_amdgcn_mfma_f32_32x32x16_bf16(ah, bl0, acc[g0], 0, 0, 0);
        acc[g1] = __builtin_amdgcn_mfma_f32_32x32x16_bf16(ah, bl1, acc[g1], 0, 0, 0);
      }
    }
#pragma unroll
    for (int reg = 0; reg < 16; ++reg) {
      int row32 = (reg & 3) + ((reg >> 2) << 3) + (hs << 2);
      float c = c_reg[reg], h;
      lstm_act(acc[0][reg], acc[1][reg], acc[2][reg], acc[3][reg], c, h);
      c_reg[reg] = c;
      unsigned short hi, lo;
      split_trunc(h, hi, lo);
      hfh[nbuf][coff + row32 * 8] = hi;
      hfl[nbuf][coff + row32 * 8] = lo;
      if (t == NHIST - 1) {
        hout[(b0 + row32) * HH + col] = h;
        cout[(b0 + row32) * HH + col] = c;
      }
    }
    __syncthreads();
    buf = nbuf;
  }
}

// -------------------------------- MC kernel --------------------------------
// Dual-chain: one block advances samples sA=2*sp and sB=2*sp+1 for the same
// 32-row batch chunk. B fragments are loaded once per kb and feed both
// chains' MFMAs (24 per kb). Wave0 runs chain-A tail, wave1 chain-B tail.
__launch_bounds__(256, 2)
__global__ void mc_kernel(const float* __restrict__ ret,
                          const float* __restrict__ W_ih,
                          const float* __restrict__ bias,
                          const unsigned short* __restrict__ Bhi,
                          const unsigned short* __restrict__ Blo,
                          const unsigned short* __restrict__ Bmu,
                          const float* __restrict__ hin,
                          const float* __restrict__ cin,
                          const float* __restrict__ b_mu,
                          const float* __restrict__ b_ls,
                          const uint32_t* __restrict__ keys,
                          float* __restrict__ accum) {
  __shared__ unsigned short hfhA[2][HFN];
  __shared__ unsigned short hflA[HFN];
  __shared__ unsigned short hfhB[2][HFN];
  __shared__ unsigned short hflB[HFN];
  __shared__ float x_sA[32], mu_sA[32], ls_sA[32];
  __shared__ float x_sB[32], mu_sB[32], ls_sB[32];

  const int tid  = threadIdx.x;
  const int lane = tid & 63;
  const int cg   = tid >> 6;
  const int hs   = lane >> 5;
  const int m    = lane & 31;
  const int col  = (cg << 5) + m;

  const int sp = blockIdx.x >> 8;
  const int b0 = (blockIdx.x & 255) << 5;
  const int sA = sp * 2, sB = sp * 2 + 1;

  float wih_r[4], bb_r[4];
#pragma unroll
  for (int gi = 0; gi < 4; ++gi) {
    float sc = (gi == 2) ? L2E2 : -L2E;
    wih_r[gi] = W_ih[(gi << 7) + col] * sc;
    bb_r[gi]  = bias[(gi << 7) + col] * sc;
  }
  const float bmu = b_mu[0], bls = b_ls[0];

  const int coff = (col >> 4) * SKB + ((col >> 3) & 1) * SHS + (col & 7);
  const int aoff = hs * SHS + m * 8;

  // init: both chains start from the same (h, c) per the reference
  float cA[16], cB[16];
#pragma unroll
  for (int reg = 0; reg < 16; ++reg) {
    int row32 = (reg & 3) + ((reg >> 2) << 3) + (hs << 2);
    int grow = b0 + row32;
    float hv = hin[grow * HH + col];
    float cv = cin[grow * HH + col];
    cA[reg] = cv; cB[reg] = cv;
    unsigned short hi, lo;
    split_trunc(hv, hi, lo);
    hfhA[0][coff + row32 * 8] = hi;
    hflA[coff + row32 * 8] = lo;
    hfhB[0][coff + row32 * 8] = hi;
    hflB[coff + row32 * 8] = lo;
  }
  if (tid < 32) {
    float xv = ret[126 * NB + b0 + tid];
    x_sA[tid] = xv; x_sB[tid] = xv;
  }
  float logw = 0.0f, outv = 0.0f;
  __syncthreads();

  int buf = 0;
#pragma unroll 1
  for (int t = 0; t < NSTEP; ++t) {
    const int nbuf = buf ^ 1;

    // ---- fused gate matmul for both chains; each B frag feeds 24 MFMAs
    facc accA[4], accB[4];
#pragma unroll
    for (int gi = 0; gi < 4; ++gi)
#pragma unroll
      for (int e = 0; e < 16; ++e) { accA[gi][e] = 0.0f; accB[gi][e] = 0.0f; }
#pragma unroll 2
    for (int kb = 0; kb < 8; ++kb) {
      bfrag ahA = *(const bfrag*)&hfhA[buf][kb * SKB + aoff];
      bfrag alA = *(const bfrag*)&hflA[kb * SKB + aoff];
      bfrag ahB = *(const bfrag*)&hfhB[buf][kb * SKB + aoff];
      bfrag alB = *(const bfrag*)&hflB[kb * SKB + aoff];
#pragma unroll
      for (int gp = 0; gp < 2; ++gp) {
        const int g0 = 2 * gp, g1 = 2 * gp + 1;
        const int off0 = ((((g0 << 2) + cg) << 3) + kb) * 512 + lane * 8;
        const int off1 = ((((g1 << 2) + cg) << 3) + kb) * 512 + lane * 8;
        bfrag bh0 = *(const bfrag*)&Bhi[off0];
        bfrag bl0 = *(const bfrag*)&Blo[off0];
        bfrag bh1 = *(const bfrag*)&Bhi[off1];
        bfrag bl1 = *(const bfrag*)&Blo[off1];
        accA[g0] = __builtin_amdgcn_mfma_f32_32x32x16_bf16(ahA, bh0, accA[g0], 0, 0, 0);
        accB[g0] = __builtin_amdgcn_mfma_f32_32x32x16_bf16(ahB, bh0, accB[g0], 0, 0, 0);
        accA[g1] = __builtin_amdgcn_mfma_f32_32x32x16_bf16(ahA, bh1, accA[g1], 0, 0, 0);
        accB[g1] = __builtin_amdgcn_mfma_f32_32x32x16_bf16(ahB, bh1, accB[g1], 0, 0, 0);
        accA[g0] = __builtin_amdgcn_mfma_f32_32x32x16_bf16(alA, bh0, accA[g0], 0, 0, 0);
        accB[g0] = __builtin_amdgcn_mfma_f32_32x32x16_bf16(alB, bh0, accB[g0], 0, 0, 0);
        accA[g1] = __builtin_amdgcn_mfma_f32_32x32x16_bf16(alA, bh1, accA[g1], 0, 0, 0);
        accB[g1] = __builtin_amdgcn_mfma_f32_32x32x16_bf16(alB, bh1, accB[g1], 0, 0, 0);
        accA[g0] = __builtin_amdgcn_mfma_f32_32x32x16_bf16(ahA, bl0, accA[g0], 0, 0, 0);
        accB[g0] = __builtin_amdgcn_mfma_f32_32x32x16_bf16(ahB, bl0, accB[g0], 0, 0, 0);
        accA[g1] = __builtin_amdgcn_mfma_f32_32x32x16_bf16(ahA, bl1, accA[g1], 0, 0, 0);
        accB[g1] = __builtin_amdgcn_mfma_f32_32x32x16_bf16(ahB, bl1, accB[g1], 0, 0, 0);
      }
    }
    __syncthreads();   // B1: hf* reads done; x_s*(t) visible

    // ---- epilogue chain A
#pragma unroll
    for (int reg = 0; reg < 16; ++reg) {
      int row32 = (reg & 3) + ((reg >> 2) << 3) + (hs << 2);
      float xv = x_sA[row32];
      float c = cA[reg], h;
      lstm_act(accA[0][reg] + fmaf(xv, wih_r[0], bb_r[0]),
               accA[1][reg] + fmaf(xv, wih_r[1], bb_r[1]),
               accA[2][reg] + fmaf(xv, wih_r[2], bb_r[2]),
               accA[3][reg] + fmaf(xv, wih_r[3], bb_r[3]), c, h);
      cA[reg] = c;
      unsigned short hi, lo;
      split_trunc(h, hi, lo);
      hfhA[nbuf][coff + row32 * 8] = hi;
      hflA[coff + row32 * 8] = lo;
    }
    // ---- epilogue chain B
#pragma unroll
    for (int reg = 0; reg < 16; ++reg) {
      int row32 = (reg & 3) + ((reg >> 2) << 3) + (hs << 2);
      float xv = x_sB[row32];
      float c = cB[reg], h;
      lstm_act(accB[0][reg] + fmaf(xv, wih_r[0], bb_r[0]),
               accB[1][reg] + fmaf(xv, wih_r[1], bb_r[1]),
               accB[2][reg] + fmaf(xv, wih_r[2], bb_r[2]),
               accB[3][reg] + fmaf(xv, wih_r[3], bb_r[3]), c, h);
      cB[reg] = c;
      unsigned short hi, lo;
      split_trunc(h, hi, lo);
      hfhB[nbuf][coff + row32 * 8] = hi;
      hflB[coff + row32 * 8] = lo;
    }
    __syncthreads();   // B2: h(t+1) frags visible for both chains

    if (tid < 128) {   // wave0: chain A tail; wave1: chain B tail
      const unsigned short* hfn;
      float *mu_p, *ls_p, *x_p;
      int s;
      if (tid < 64) { hfn = hfhA[nbuf]; mu_p = mu_sA; ls_p = ls_sA; x_p = x_sA; s = sA; }
      else          { hfn = hfhB[nbuf]; mu_p = mu_sB; ls_p = ls_sB; x_p = x_sB; s = sB; }
      facc am;
#pragma unroll
      for (int e = 0; e < 16; ++e) am[e] = 0.0f;
#pragma unroll 2
      for (int kb = 0; kb < 8; ++kb) {
        const bfrag bm = *(const bfrag*)&Bmu[kb * 512 + lane * 8];
        const bfrag a0 = *(const bfrag*)&hfn[kb * SKB + aoff];
        am = __builtin_amdgcn_mfma_f32_32x32x16_bf16(a0, bm, am, 0, 0, 0);
      }
      if (m < 2) {
        float* dst = (m == 0) ? mu_p : ls_p;
#pragma unroll
        for (int reg = 0; reg < 16; ++reg)
          dst[(reg & 3) + ((reg >> 2) << 3) + (hs << 2)] = am[reg];
      }
      // same-wave LDS RAW: compiler inserts lgkmcnt wait
      float mu  = mu_p[m] + bmu;
      float lsc = fminf(fmaxf(ls_p[m] + bls, -5.0f), 2.0f);
      float sg  = __expf(lsc);
      const int ko = 2 * (s * NSTEP + t);
      uint32_t k0 = keys[ko];
      uint32_t k1 = keys[ko + 1];
      float z  = normal32(k0, k1, (uint32_t)(b0 + m));
      float xn = fmaf(sg, z + 0.5f, mu);
      logw -= fmaf(0.5f, z, 0.125f);
      if (t == TCAP) outv = xn;
      if (lane < 32) x_p[lane] = xn;   // visible to consumers via next B1
    }
    buf = nbuf;
  }

  if (tid < 128 && lane < 32) {        // wave0 -> sample A, wave1 -> sample B
    float wt = __expf(logw);
    float ow = outv * wt;
    int b = b0 + lane;
    atomicAdd(&accum[0 * NB + b], wt);
    atomicAdd(&accum[1 * NB + b], ow);
    atomicAdd(&accum[2 * NB + b], wt * wt);
    atomicAdd(&accum[3 * NB + b], ow * ow);
    atomicAdd(&accum[4 * NB + b], outv * wt * wt);
  }
}

// ------------------------------- final kernel ------------------------------
__global__ void final_kernel(const float* __restrict__ accum,
                             float* __restrict__ out) {
  int b = blockIdx.x * blockDim.x + threadIdx.x;
  if (b >= NB) return;
  float sw  = accum[0 * NB + b];
  float sm1 = accum[1 * NB + b];
  float sqw = accum[2 * NB + b];
  float sm2 = accum[3 * NB + b];
  float shm = accum[4 * NB + b];
  float mean = sm1 / sw;
  float sem = sm2 + sqw * mean * mean - 2.0f * shm * mean;
  sem = sqrtf(sem / (float)(NSAMP * (NSAMP - 1)));
  out[b] = mean;
  out[NB + b] = sem;
}

// ------------------------------- launcher ----------------------------------
extern "C" void kernel_launch(void* const* d_in, const int* in_sizes, int n_in,
                              void* d_out, int out_size, void* d_ws, size_t ws_size,
                              hipStream_t stream) {
  (void)in_sizes; (void)n_in; (void)out_size; (void)ws_size;
  const float* inp  = (const float*)d_in[0];
  const float* pert = (const float*)d_in[1];
  const float* W_ih = (const float*)d_in[2];
  const float* W_hh = (const float*)d_in[3];
  const float* bias = (const float*)d_in[4];
  const float* w_mu = (const float*)d_in[5];
  const float* b_mu = (const float*)d_in[6];
  const float* w_ls = (const float*)d_in[7];
  const float* b_ls = (const float*)d_in[8];

  char* ws = (char*)d_ws;
  float* ret = (float*)ws;        ws += (size_t)NRET * NB * sizeof(float);
  float* hh  = (float*)ws;        ws += (size_t)NB * HH * sizeof(float);
  float* cc  = (float*)ws;        ws += (size_t)NB * HH * sizeof(float);
  uint32_t* keys = (uint32_t*)ws; ws += (size_t)NSAMP * NSTEP * 2 * sizeof(uint32_t);
  float* accum = (float*)ws;      ws += (size_t)5 * NB * sizeof(float);
  unsigned short* Bhi = (unsigned short*)ws; ws += 65536 * sizeof(unsigned short);
  unsigned short* Blo = (unsigned short*)ws; ws += 65536 * sizeof(unsigned short);
  unsigned short* Bmu = (unsigned short*)ws; ws += 4096 * sizeof(unsigned short);

  hipMemsetAsync(accum, 0, (size_t)5 * NB * sizeof(float), stream);
  returns_kernel<<<(NRET * NB + 255) / 256, 256, 0, stream>>>(inp, pert, ret);
  keys_kernel<<<(NSAMP * NSTEP + 255) / 256, 256, 0, stream>>>(keys);
  pack_kernel<<<(65536 + 4096) / 256, 256, 0, stream>>>(W_hh, w_mu, w_ls, Bhi, Blo, Bmu);
  hist_kernel<<<NB / 32, 256, 0, stream>>>(ret, W_ih, bias, Bhi, Blo, hh, cc);
  mc_kernel<<<NSAMP * (NB / 32) / 2, 256, 0, stream>>>(ret, W_ih, bias, Bhi, Blo, Bmu,
      hh, cc, b_mu, b_ls, keys, accum);
  final_kernel<<<NB / 256, 256, 0, stream>>>(accum, (float*)d_out);
}

// Round 6
// 7589.321 us; speedup vs baseline: 4.6539x; 1.0095x over previous
//
#include <hip/hip_runtime.h>
#include <stdint.h>
#include <math.h>

// ---------------------------------------------------------------------------
// Round 23: VALU micro-cuts on R22 (7662 us, MfmaUtil 42 / VALUBusy 48).
// Two changes, no structure/sync/register-budget change:
//  1) acc init = per-gate bias (accvgpr write of bb_r instead of 0 is free);
//     epilogue gate fold becomes fmaf(xv, wih, acc) -- 1 op/gate not 2.
//  2) per-block z-table: all 2x20x32 Gaussian z values precomputed at block
//     init into LDS (5/thread, ~1k cyc once); per-step tail loses the whole
//     threefry+erfinv (~400 cyc on waves 0/1), becomes 8 MFMAs + few ops.
// LDS 51.5 -> 56.8 KB, still 2 blocks/CU. Expected -700..900 VALU
// cyc/wave-step = 3-5% wall.
// ---------------------------------------------------------------------------

#define HH     128
#define NG     512
#define NB     8192
#define NSAMP  100
#define NSTEP  20
#define TCAP   18
#define NHIST  126
#define NRET   127

#define L2E  1.44269504f
#define L2E2 2.88539008f

using bfrag = __attribute__((ext_vector_type(8))) short;   // 8 bf16 = 4 VGPRs
using facc  = __attribute__((ext_vector_type(16))) float;  // 16 f32 acc

// LDS frag strides (shorts): per-(kb,hs) region 264 (8 pad), per-kb 528.
#define SHS 264
#define SKB 528
#define HFN 4224   // 8 kb * 528

// ----------------------------- threefry2x32 --------------------------------
__device__ __forceinline__ void tf2x32(uint32_t k0, uint32_t k1,
                                       uint32_t x0, uint32_t x1,
                                       uint32_t &y0, uint32_t &y1) {
  uint32_t ks2 = k0 ^ k1 ^ 0x1BD11BDAu;
  x0 += k0; x1 += k1;
#define RR(r) { x0 += x1; x1 = (x1 << (r)) | (x1 >> (32 - (r))); x1 ^= x0; }
  RR(13) RR(15) RR(26) RR(6)   x0 += k1;  x1 += ks2 + 1u;
  RR(17) RR(29) RR(16) RR(24)  x0 += ks2; x1 += k0  + 2u;
  RR(13) RR(15) RR(26) RR(6)   x0 += k0;  x1 += k1  + 3u;
  RR(17) RR(29) RR(16) RR(24)  x0 += k1;  x1 += ks2 + 4u;
  RR(13) RR(15) RR(26) RR(6)   x0 += ks2; x1 += k0  + 5u;
#undef RR
  y0 = x0; y1 = x1;
}

__device__ __forceinline__ float erfinv32(float x) {
  float w = -__logf(fmaxf(1.0f - x * x, 1e-37f));
  float p;
  if (w < 5.0f) {
    w = w - 2.5f;
    p = 2.81022636e-08f;
    p = fmaf(p, w, 3.43273939e-07f);
    p = fmaf(p, w, -3.5233877e-06f);
    p = fmaf(p, w, -4.39150654e-06f);
    p = fmaf(p, w, 0.00021858087f);
    p = fmaf(p, w, -0.00125372503f);
    p = fmaf(p, w, -0.00417768164f);
    p = fmaf(p, w, 0.246640727f);
    p = fmaf(p, w, 1.50140941f);
  } else {
    w = sqrtf(w) - 3.0f;
    p = -0.000200214257f;
    p = fmaf(p, w, 0.000100950558f);
    p = fmaf(p, w, 0.00134934322f);
    p = fmaf(p, w, -0.00367342844f);
    p = fmaf(p, w, 0.00573950773f);
    p = fmaf(p, w, -0.0076224613f);
    p = fmaf(p, w, 0.00943887047f);
    p = fmaf(p, w, 1.00167406f);
    p = fmaf(p, w, 2.83297682f);
  }
  return p * x;
}

__device__ __forceinline__ float normal32(uint32_t k0, uint32_t k1, uint32_t idx) {
  uint32_t y0, y1;
  tf2x32(k0, k1, 0u, idx, y0, y1);
  uint32_t bits = y0 ^ y1;
  float f = __uint_as_float((bits >> 9) | 0x3f800000u) - 1.0f;
  const float lo = __uint_as_float(0xBF7FFFFFu);
  float u = fmaxf(lo, f * 2.0f + lo);
  return 1.41421356f * erfinv32(u);
}

// RNE bf16 (one-time B pack only)
__device__ __forceinline__ unsigned short f2bf(float x) {
  uint32_t u = __float_as_uint(x);
  uint32_t r = u + 0x7fffu + ((u >> 16) & 1u);
  return (unsigned short)(r >> 16);
}
__device__ __forceinline__ float bf2f(unsigned short h) {
  return __uint_as_float(((uint32_t)h) << 16);
}

// truncation split: hi = top16(h); lo = top16(h - hi) (Sterbenz-exact sub)
__device__ __forceinline__ void split_trunc(float h, unsigned short &hi,
                                            unsigned short &lo) {
  uint32_t u = __float_as_uint(h);
  hi = (unsigned short)(u >> 16);
  float hv = __uint_as_float(u & 0xFFFF0000u);
  lo = (unsigned short)(__float_as_uint(h - hv) >> 16);
}

// Merged LSTM activation core. Inputs are PRE-SCALED gate values:
//   yi = -L*i, yf = -L*f, yg = 2L*g, yo = -L*o   (L = log2 e)
// Computes c' = sig(f)*c + sig(i)*tanh(g), h = sig(o)*tanh(c').
// 5 exp2 + 3 rcp per element; saturation-safe via clamp on tanh-side exps.
__device__ __forceinline__ void lstm_act(float yi, float yf, float yg, float yo,
                                         float &c, float &h) {
  float Ei = __builtin_amdgcn_exp2f(yi);
  float Eg = __builtin_amdgcn_exp2f(fminf(yg, 80.0f));
  float Ef = __builtin_amdgcn_exp2f(yf);
  float Eo = __builtin_amdgcn_exp2f(yo);
  float P1 = (Eg - 1.0f) * __builtin_amdgcn_rcpf((1.0f + Ei) * (1.0f + Eg));
  c = fmaf(c, __builtin_amdgcn_rcpf(1.0f + Ef), P1);
  float Ec = __builtin_amdgcn_exp2f(fminf(L2E2 * c, 80.0f));
  h = (Ec - 1.0f) * __builtin_amdgcn_rcpf((1.0f + Eo) * (1.0f + Ec));
}

// ------------------------------- small kernels -----------------------------
__global__ void returns_kernel(const float* __restrict__ inp,
                               const float* __restrict__ pert,
                               float* __restrict__ ret) {
  int i = blockIdx.x * blockDim.x + threadIdx.x;
  if (i >= NRET * NB) return;
  int s = i / NB, b = i - s * NB;
  float p0 = inp[s * NB + b] * (1.0f + pert[s * NB + b]);
  float p1 = inp[(s + 1) * NB + b] * (1.0f + pert[(s + 1) * NB + b]);
  ret[i] = p1 - p0;
}

__global__ void keys_kernel(uint32_t* __restrict__ keys) {
  int id = blockIdx.x * blockDim.x + threadIdx.x;
  if (id >= NSAMP * NSTEP) return;
  int s = id / NSTEP, t = id - s * NSTEP;
  uint32_t sk0, sk1, k0, k1;
  tf2x32(0u, 42u, 0u, (uint32_t)s, sk0, sk1);
  tf2x32(sk0, sk1, 0u, (uint32_t)t, k0, k1);
  keys[2 * id] = k0; keys[2 * id + 1] = k1;
}

// B-fragment pack (RNE): Bhi/Blo[((gct*8+kb)*64+lane)*8+j]
// W_hh is PRE-SCALED per gate: gates i,f,o by -L, gate g by +2L (exact
// linear transform so exp2 applies directly to the MFMA output).
__global__ void pack_kernel(const float* __restrict__ W_hh,
                            const float* __restrict__ w_mu,
                            const float* __restrict__ w_ls,
                            unsigned short* __restrict__ Bhi,
                            unsigned short* __restrict__ Blo,
                            unsigned short* __restrict__ Bmu) {
  int idx = blockIdx.x * blockDim.x + threadIdx.x;
  if (idx < 65536) {
    int j = idx & 7, lane = (idx >> 3) & 63, kb = (idx >> 9) & 7, gct = idx >> 12;
    int k = kb * 16 + ((lane >> 5) << 3) + j;
    int g = (gct << 5) + (lane & 31);
    float sc = ((gct >> 2) == 2) ? L2E2 : -L2E;
    float w = W_hh[k * NG + g] * sc;
    unsigned short hi = f2bf(w);
    unsigned short lo = f2bf(w - bf2f(hi));
    Bhi[idx] = hi; Blo[idx] = lo;
  } else if (idx < 65536 + 4096) {
    int i2 = idx - 65536;
    int j = i2 & 7, lane = (i2 >> 3) & 63, kb = (i2 >> 9) & 7;
    int k = kb * 16 + ((lane >> 5) << 3) + j;
    int col = lane & 31;
    float v = (col == 0) ? w_mu[k] : (col == 1 ? w_ls[k] : 0.0f);
    Bmu[i2] = f2bf(v);
  }
}

// ------------------------------ history kernel -----------------------------
__launch_bounds__(256, 1)
__global__ void hist_kernel(const float* __restrict__ ret,
                            const float* __restrict__ W_ih,
                            const float* __restrict__ bias,
                            const unsigned short* __restrict__ Bhi,
                            const unsigned short* __restrict__ Blo,
                            float* __restrict__ hout,
                            float* __restrict__ cout) {
  __shared__ unsigned short hfh[2][HFN];
  __shared__ unsigned short hfl[2][HFN];

  const int tid  = threadIdx.x;
  const int lane = tid & 63;
  const int cg   = tid >> 6;
  const int hs   = lane >> 5;
  const int m    = lane & 31;
  const int col  = (cg << 5) + m;
  const int b0   = blockIdx.x << 5;

  float wih_r[4], bb_r[4];
#pragma unroll
  for (int gi = 0; gi < 4; ++gi) {
    float sc = (gi == 2) ? L2E2 : -L2E;
    wih_r[gi] = W_ih[(gi << 7) + col] * sc;
    bb_r[gi]  = bias[(gi << 7) + col] * sc;
  }

  const int coff = (col >> 4) * SKB + ((col >> 3) & 1) * SHS + (col & 7);
  const int aoff = hs * SHS + m * 8;

  float c_reg[16];
#pragma unroll
  for (int reg = 0; reg < 16; ++reg) {
    int row32 = (reg & 3) + ((reg >> 2) << 3) + (hs << 2);
    c_reg[reg] = 0.0f;
    hfh[0][coff + row32 * 8] = 0;
    hfl[0][coff + row32 * 8] = 0;
  }
  __syncthreads();

  int buf = 0;
#pragma unroll 1
  for (int t = 0; t < NHIST; ++t) {
    const int nbuf = buf ^ 1;
    facc acc[4];
#pragma unroll
    for (int reg = 0; reg < 16; ++reg) {
      int row32 = (reg & 3) + ((reg >> 2) << 3) + (hs << 2);
      float xv = ret[t * NB + b0 + row32];
#pragma unroll
      for (int gi = 0; gi < 4; ++gi)
        acc[gi][reg] = fmaf(xv, wih_r[gi], bb_r[gi]);
    }
#pragma unroll 1
    for (int kb = 0; kb < 8; ++kb) {
      bfrag ah = *(const bfrag*)&hfh[buf][kb * SKB + aoff];
      bfrag al = *(const bfrag*)&hfl[buf][kb * SKB + aoff];
#pragma unroll
      for (int gp = 0; gp < 2; ++gp) {
        const int g0 = 2 * gp, g1 = 2 * gp + 1;
        const int off0 = ((((g0 << 2) + cg) << 3) + kb) * 512 + lane * 8;
        const int off1 = ((((g1 << 2) + cg) << 3) + kb) * 512 + lane * 8;
        bfrag bh0 = *(const bfrag*)&Bhi[off0];
        bfrag bl0 = *(const bfrag*)&Blo[off0];
        bfrag bh1 = *(const bfrag*)&Bhi[off1];
        bfrag bl1 = *(const bfrag*)&Blo[off1];
        acc[g0] = __builtin_amdgcn_mfma_f32_32x32x16_bf16(ah, bh0, acc[g0], 0, 0, 0);
        acc[g1] = __builtin_amdgcn_mfma_f32_32x32x16_bf16(ah, bh1, acc[g1], 0, 0, 0);
        acc[g0] = __builtin_amdgcn_mfma_f32_32x32x16_bf16(al, bh0, acc[g0], 0, 0, 0);
        acc[g1] = __builtin_amdgcn_mfma_f32_32x32x16_bf16(al, bh1, acc[g1], 0, 0, 0);
        acc[g0] = __builtin_amdgcn_mfma_f32_32x32x16_bf16(ah, bl0, acc[g0], 0, 0, 0);
        acc[g1] = __builtin_amdgcn_mfma_f32_32x32x16_bf16(ah, bl1, acc[g1], 0, 0, 0);
      }
    }
#pragma unroll
    for (int reg = 0; reg < 16; ++reg) {
      int row32 = (reg & 3) + ((reg >> 2) << 3) + (hs << 2);
      float c = c_reg[reg], h;
      lstm_act(acc[0][reg], acc[1][reg], acc[2][reg], acc[3][reg], c, h);
      c_reg[reg] = c;
      unsigned short hi, lo;
      split_trunc(h, hi, lo);
      hfh[nbuf][coff + row32 * 8] = hi;
      hfl[nbuf][coff + row32 * 8] = lo;
      if (t == NHIST - 1) {
        hout[(b0 + row32) * HH + col] = h;
        cout[(b0 + row32) * HH + col] = c;
      }
    }
    __syncthreads();
    buf = nbuf;
  }
}

// -------------------------------- MC kernel --------------------------------
// Dual-chain: one block advances samples sA=2*sp and sB=2*sp+1 for the same
// 32-row batch chunk. B fragments are loaded once per kb and feed both
// chains' MFMAs (24 per kb). Wave0 runs chain-A tail, wave1 chain-B tail.
// z values precomputed per block into LDS (zbA/zbB).
__launch_bounds__(256, 2)
__global__ void mc_kernel(const float* __restrict__ ret,
                          const float* __restrict__ W_ih,
                          const float* __restrict__ bias,
                          const unsigned short* __restrict__ Bhi,
                          const unsigned short* __restrict__ Blo,
                          const unsigned short* __restrict__ Bmu,
                          const float* __restrict__ hin,
                          const float* __restrict__ cin,
                          const float* __restrict__ b_mu,
                          const float* __restrict__ b_ls,
                          const uint32_t* __restrict__ keys,
                          float* __restrict__ accum) {
  __shared__ unsigned short hfhA[2][HFN];
  __shared__ unsigned short hflA[HFN];
  __shared__ unsigned short hfhB[2][HFN];
  __shared__ unsigned short hflB[HFN];
  __shared__ float x_sA[32], mu_sA[32], ls_sA[32];
  __shared__ float x_sB[32], mu_sB[32], ls_sB[32];
  __shared__ float zbA[NSTEP][32];
  __shared__ float zbB[NSTEP][32];

  const int tid  = threadIdx.x;
  const int lane = tid & 63;
  const int cg   = tid >> 6;
  const int hs   = lane >> 5;
  const int m    = lane & 31;
  const int col  = (cg << 5) + m;

  const int sp = blockIdx.x >> 8;
  const int b0 = (blockIdx.x & 255) << 5;
  const int sA = sp * 2, sB = sp * 2 + 1;

  float wih_r[4], bb_r[4];
#pragma unroll
  for (int gi = 0; gi < 4; ++gi) {
    float sc = (gi == 2) ? L2E2 : -L2E;
    wih_r[gi] = W_ih[(gi << 7) + col] * sc;
    bb_r[gi]  = bias[(gi << 7) + col] * sc;
  }
  const float bmu = b_mu[0], bls = b_ls[0];

  const int coff = (col >> 4) * SKB + ((col >> 3) & 1) * SHS + (col & 7);
  const int aoff = hs * SHS + m * 8;

  // init: both chains start from the same (h, c) per the reference
  float cA[16], cB[16];
#pragma unroll
  for (int reg = 0; reg < 16; ++reg) {
    int row32 = (reg & 3) + ((reg >> 2) << 3) + (hs << 2);
    int grow = b0 + row32;
    float hv = hin[grow * HH + col];
    float cv = cin[grow * HH + col];
    cA[reg] = cv; cB[reg] = cv;
    unsigned short hi, lo;
    split_trunc(hv, hi, lo);
    hfhA[0][coff + row32 * 8] = hi;
    hflA[coff + row32 * 8] = lo;
    hfhB[0][coff + row32 * 8] = hi;
    hflB[coff + row32 * 8] = lo;
  }
  if (tid < 32) {
    float xv = ret[126 * NB + b0 + tid];
    x_sA[tid] = xv; x_sB[tid] = xv;
  }
  // per-block z table: 2 chains x 20 steps x 32 rows = 1280 values, 5/thread
#pragma unroll
  for (int j = 0; j < 5; ++j) {
    int q = tid + (j << 8);            // [0,1280)
    int cs = (q >= 640) ? 1 : 0;
    int r  = q - (cs ? 640 : 0);       // [0,640)
    int tt = r >> 5;                   // 0..19
    int m2 = r & 31;
    int s  = cs ? sB : sA;
    int ko = 2 * (s * NSTEP + tt);
    float z = normal32(keys[ko], keys[ko + 1], (uint32_t)(b0 + m2));
    if (cs) zbB[tt][m2] = z; else zbA[tt][m2] = z;
  }
  float logw = 0.0f, outv = 0.0f;
  __syncthreads();

  int buf = 0;
#pragma unroll 1
  for (int t = 0; t < NSTEP; ++t) {
    const int nbuf = buf ^ 1;

    // ---- fused gate matmul for both chains; each B frag feeds 24 MFMAs.
    // acc init = pre-scaled bias (free accvgpr write; saves epi adds).
    facc accA[4], accB[4];
#pragma unroll
    for (int gi = 0; gi < 4; ++gi)
#pragma unroll
      for (int e = 0; e < 16; ++e) { accA[gi][e] = bb_r[gi]; accB[gi][e] = bb_r[gi]; }
#pragma unroll 2
    for (int kb = 0; kb < 8; ++kb) {
      bfrag ahA = *(const bfrag*)&hfhA[buf][kb * SKB + aoff];
      bfrag alA = *(const bfrag*)&hflA[kb * SKB + aoff];
      bfrag ahB = *(const bfrag*)&hfhB[buf][kb * SKB + aoff];
      bfrag alB = *(const bfrag*)&hflB[kb * SKB + aoff];
#pragma unroll
      for (int gp = 0; gp < 2; ++gp) {
        const int g0 = 2 * gp, g1 = 2 * gp + 1;
        const int off0 = ((((g0 << 2) + cg) << 3) + kb) * 512 + lane * 8;
        const int off1 = ((((g1 << 2) + cg) << 3) + kb) * 512 + lane * 8;
        bfrag bh0 = *(const bfrag*)&Bhi[off0];
        bfrag bl0 = *(const bfrag*)&Blo[off0];
        bfrag bh1 = *(const bfrag*)&Bhi[off1];
        bfrag bl1 = *(const bfrag*)&Blo[off1];
        accA[g0] = __builtin_amdgcn_mfma_f32_32x32x16_bf16(ahA, bh0, accA[g0], 0, 0, 0);
        accB[g0] = __builtin_amdgcn_mfma_f32_32x32x16_bf16(ahB, bh0, accB[g0], 0, 0, 0);
        accA[g1] = __builtin_amdgcn_mfma_f32_32x32x16_bf16(ahA, bh1, accA[g1], 0, 0, 0);
        accB[g1] = __builtin_amdgcn_mfma_f32_32x32x16_bf16(ahB, bh1, accB[g1], 0, 0, 0);
        accA[g0] = __builtin_amdgcn_mfma_f32_32x32x16_bf16(alA, bh0, accA[g0], 0, 0, 0);
        accB[g0] = __builtin_amdgcn_mfma_f32_32x32x16_bf16(alB, bh0, accB[g0], 0, 0, 0);
        accA[g1] = __builtin_amdgcn_mfma_f32_32x32x16_bf16(alA, bh1, accA[g1], 0, 0, 0);
        accB[g1] = __builtin_amdgcn_mfma_f32_32x32x16_bf16(alB, bh1, accB[g1], 0, 0, 0);
        accA[g0] = __builtin_amdgcn_mfma_f32_32x32x16_bf16(ahA, bl0, accA[g0], 0, 0, 0);
        accB[g0] = __builtin_amdgcn_mfma_f32_32x32x16_bf16(ahB, bl0, accB[g0], 0, 0, 0);
        accA[g1] = __builtin_amdgcn_mfma_f32_32x32x16_bf16(ahA, bl1, accA[g1], 0, 0, 0);
        accB[g1] = __builtin_amdgcn_mfma_f32_32x32x16_bf16(ahB, bl1, accB[g1], 0, 0, 0);
      }
    }
    __syncthreads();   // B1: hf* reads done; x_s*(t) visible

    // ---- epilogue chain A
#pragma unroll
    for (int reg = 0; reg < 16; ++reg) {
      int row32 = (reg & 3) + ((reg >> 2) << 3) + (hs << 2);
      float xv = x_sA[row32];
      float c = cA[reg], h;
      lstm_act(fmaf(xv, wih_r[0], accA[0][reg]),
               fmaf(xv, wih_r[1], accA[1][reg]),
               fmaf(xv, wih_r[2], accA[2][reg]),
               fmaf(xv, wih_r[3], accA[3][reg]), c, h);
      cA[reg] = c;
      unsigned short hi, lo;
      split_trunc(h, hi, lo);
      hfhA[nbuf][coff + row32 * 8] = hi;
      hflA[coff + row32 * 8] = lo;
    }
    // ---- epilogue chain B
#pragma unroll
    for (int reg = 0; reg < 16; ++reg) {
      int row32 = (reg & 3) + ((reg >> 2) << 3) + (hs << 2);
      float xv = x_sB[row32];
      float c = cB[reg], h;
      lstm_act(fmaf(xv, wih_r[0], accB[0][reg]),
               fmaf(xv, wih_r[1], accB[1][reg]),
               fmaf(xv, wih_r[2], accB[2][reg]),
               fmaf(xv, wih_r[3], accB[3][reg]), c, h);
      cB[reg] = c;
      unsigned short hi, lo;
      split_trunc(h, hi, lo);
      hfhB[nbuf][coff + row32 * 8] = hi;
      hflB[coff + row32 * 8] = lo;
    }
    __syncthreads();   // B2: h(t+1) frags visible for both chains

    if (tid < 128) {   // wave0: chain A tail; wave1: chain B tail
      const unsigned short* hfn;
      float *mu_p, *ls_p, *x_p;
      const float* zrow;
      if (tid < 64) { hfn = hfhA[nbuf]; mu_p = mu_sA; ls_p = ls_sA; x_p = x_sA; zrow = &zbA[t][0]; }
      else          { hfn = hfhB[nbuf]; mu_p = mu_sB; ls_p = ls_sB; x_p = x_sB; zrow = &zbB[t][0]; }
      facc am;
#pragma unroll
      for (int e = 0; e < 16; ++e) am[e] = 0.0f;
#pragma unroll 2
      for (int kb = 0; kb < 8; ++kb) {
        const bfrag bm = *(const bfrag*)&Bmu[kb * 512 + lane * 8];
        const bfrag a0 = *(const bfrag*)&hfn[kb * SKB + aoff];
        am = __builtin_amdgcn_mfma_f32_32x32x16_bf16(a0, bm, am, 0, 0, 0);
      }
      if (m < 2) {
        float* dst = (m == 0) ? mu_p : ls_p;
#pragma unroll
        for (int reg = 0; reg < 16; ++reg)
          dst[(reg & 3) + ((reg >> 2) << 3) + (hs << 2)] = am[reg];
      }
      // same-wave LDS RAW: compiler inserts lgkmcnt wait
      float mu  = mu_p[m] + bmu;
      float lsc = fminf(fmaxf(ls_p[m] + bls, -5.0f), 2.0f);
      float sg  = __expf(lsc);
      float z   = zrow[m];
      float xn  = fmaf(sg, z + 0.5f, mu);
      logw -= fmaf(0.5f, z, 0.125f);
      if (t == TCAP) outv = xn;
      if (lane < 32) x_p[lane] = xn;   // visible to consumers via next B1
    }
    buf = nbuf;
  }

  if (tid < 128 && lane < 32) {        // wave0 -> sample A, wave1 -> sample B
    float wt = __expf(logw);
    float ow = outv * wt;
    int b = b0 + lane;
    atomicAdd(&accum[0 * NB + b], wt);
    atomicAdd(&accum[1 * NB + b], ow);
    atomicAdd(&accum[2 * NB + b], wt * wt);
    atomicAdd(&accum[3 * NB + b], ow * ow);
    atomicAdd(&accum[4 * NB + b], outv * wt * wt);
  }
}

// ------------------------------- final kernel ------------------------------
__global__ void final_kernel(const float* __restrict__ accum,
                             float* __restrict__ out) {
  int b = blockIdx.x * blockDim.x + threadIdx.x;
  if (b >= NB) return;
  float sw  = accum[0 * NB + b];
  float sm1 = accum[1 * NB + b];
  float sqw = accum[2 * NB + b];
  float sm2 = accum[3 * NB + b];
  float shm = accum[4 * NB + b];
  float mean = sm1 / sw;
  float sem = sm2 + sqw * mean * mean - 2.0f * shm * mean;
  sem = sqrtf(sem / (float)(NSAMP * (NSAMP - 1)));
  out[b] = mean;
  out[NB + b] = sem;
}

// ------------------------------- launcher ----------------------------------
extern "C" void kernel_launch(void* const* d_in, const int* in_sizes, int n_in,
                              void* d_out, int out_size, void* d_ws, size_t ws_size,
                              hipStream_t stream) {
  (void)in_sizes; (void)n_in; (void)out_size; (void)ws_size;
  const float* inp  = (const float*)d_in[0];
  const float* pert = (const float*)d_in[1];
  const float* W_ih = (const float*)d_in[2];
  const float* W_hh = (const float*)d_in[3];
  const float* bias = (const float*)d_in[4];
  const float* w_mu = (const float*)d_in[5];
  const float* b_mu = (const float*)d_in[6];
  const float* w_ls = (const float*)d_in[7];
  const float* b_ls = (const float*)d_in[8];

  char* ws = (char*)d_ws;
  float* ret = (float*)ws;        ws += (size_t)NRET * NB * sizeof(float);
  float* hh  = (float*)ws;        ws += (size_t)NB * HH * sizeof(float);
  float* cc  = (float*)ws;        ws += (size_t)NB * HH * sizeof(float);
  uint32_t* keys = (uint32_t*)ws; ws += (size_t)NSAMP * NSTEP * 2 * sizeof(uint32_t);
  float* accum = (float*)ws;      ws += (size_t)5 * NB * sizeof(float);
  unsigned short* Bhi = (unsigned short*)ws; ws += 65536 * sizeof(unsigned short);
  unsigned short* Blo = (unsigned short*)ws; ws += 65536 * sizeof(unsigned short);
  unsigned short* Bmu = (unsigned short*)ws; ws += 4096 * sizeof(unsigned short);

  hipMemsetAsync(accum, 0, (size_t)5 * NB * sizeof(float), stream);
  returns_kernel<<<(NRET * NB + 255) / 256, 256, 0, stream>>>(inp, pert, ret);
  keys_kernel<<<(NSAMP * NSTEP + 255) / 256, 256, 0, stream>>>(keys);
  pack_kernel<<<(65536 + 4096) / 256, 256, 0, stream>>>(W_hh, w_mu, w_ls, Bhi, Blo, Bmu);
  hist_kernel<<<NB / 32, 256, 0, stream>>>(ret, W_ih, bias, Bhi, Blo, hh, cc);
  mc_kernel<<<NSAMP * (NB / 32) / 2, 256, 0, stream>>>(ret, W_ih, bias, Bhi, Blo, Bmu,
      hh, cc, b_mu, b_ls, keys, accum);
  final_kernel<<<NB / 256, 256, 0, stream>>>(accum, (float*)d_out);
}